// Round 4
// baseline (248.445 us; speedup 1.0000x reference)
//
#include <hip/hip_runtime.h>
#include <hip/hip_bf16.h>

#define B 64
#define T 50
#define S 400
#define H 512
#define E 256
#define V 50000
#define EXT 50250
#define G3 1536

typedef __attribute__((ext_vector_type(8))) short short8;
typedef __attribute__((ext_vector_type(4))) float f32x4;

// ---- output offsets (f32 elements, return order) ----
#define O_PFINAL 0L
#define O_PGEN   3216000L
#define O_PVOCAB 3216064L
#define O_ATT    6416064L
#define O_DECH   6441664L
#define O_H      8112832L
#define O_NPA    8145600L

// ---- workspace offsets (f32 elements); total ~560K f32 = 2.24 MB ----
#define OFF_X      0L        /* B*E   */
#define OFF_G      16384L    /* B*G3  */
#define OFF_GG     114688L   /* B*G3  */
#define OFF_H      212992L   /* B*H   */
#define OFF_HW     245760L   /* B*H   */
#define OFF_HWD    278528L   /* B*H   */
#define OFF_ATTD   311296L   /* B*S   */
#define OFF_DEN    336896L   /* B*S   */
#define OFF_ENCP   362496L   /* B*4*H */
#define OFF_DEC    493568L   /* B*H   */
#define OFF_ATT    526336L   /* B*S   */
#define OFF_PG     551936L   /* 64 */
#define OFF_MAX    552000L   /* 64 */
#define OFF_SUM    552064L   /* 64 */
#define OFF_PROJBF 552128L   /* 16384 bf16 = 8192 f32 slots */

__device__ __forceinline__ float sigmoidf_(float x){ return 1.0f/(1.0f+expf(-x)); }
__device__ __forceinline__ short f2bs(float x){
    union { __hip_bfloat16 b; short s; } c; c.b = __float2bfloat16(x); return c.s;
}

// ---------------- K1a: embedding gather ----------------
__global__ void k_embed(const int* tok, const float* emb, float* x){
    int i = blockIdx.x*256 + threadIdx.x;   // B*E
    int b = i >> 8, e = i & 255;
    x[i] = emb[(long)tok[b]*E + e];
}

// ---------------- K1b: GRU gate pre-activations ----------------
// grid = B*384, 256 thr; wave computes one j of 1536
__global__ void k_gates(const float* x, const float* lh,
                        const float* Wih, const float* Whh,
                        const float* bih, const float* bhh,
                        float* g, float* Gg){
    int blk = blockIdx.x;
    int b = blk / 384, jg = blk % 384;
    int wave = threadIdx.x >> 6, lane = threadIdx.x & 63;
    int j = jg*4 + wave;
    const float* xb = x + b*E;
    float gi = 0.f, gh = 0.f;
    #pragma unroll
    for (int m = 0; m < 4; m++)
        gi += xb[lane + 64*m] * Wih[(long)j*E + lane + 64*m];
    #pragma unroll
    for (int m = 0; m < 8; m++)
        gh += lh[b*H + lane + 64*m] * Whh[(long)j*H + lane + 64*m];
    for (int off = 32; off > 0; off >>= 1){
        gi += __shfl_xor(gi, off);
        gh += __shfl_xor(gh, off);
    }
    if (lane == 0){
        g [b*G3 + j] = gi + bih[j];
        Gg[b*G3 + j] = gh + bhh[j];
    }
}

// ---------------- K1c: GRU combine -> h, hw, hwd ----------------
__global__ void k_gru(const float* g, const float* Gg, const float* lh,
                      const float* wh, const float* wd,
                      float* h, float* hw, float* hwd, float* out){
    int i = blockIdx.x*256 + threadIdx.x;   // B*H
    int b = i >> 9, k = i & 511;
    float ir = g [b*G3 + k], iz = g [b*G3 + H + k], inn = g [b*G3 + 2*H + k];
    float hr = Gg[b*G3 + k], hz = Gg[b*G3 + H + k], hn  = Gg[b*G3 + 2*H + k];
    float r = sigmoidf_(ir + hr), z = sigmoidf_(iz + hz);
    float n = tanhf(inn + r*hn);
    float hp = lh[i];
    float hv = (1.f - z)*n + z*hp;
    h[i] = hv; hw[i] = hv * wh[k]; hwd[i] = hv * wd[k];
    out[O_H + i] = hv;
    out[O_DECH + ((long)b*(T+1) + T)*H + k] = hv;
}

// ---------------- K2: att_dist = h . (w_h * enc) ----------------
// grid = B*(S/4), 256 thr; wave per s
__global__ void k_attdist(const float* hw, const float* enc,
                          float* attd, float* out){
    int b = blockIdx.x / (S/4);
    int s = (blockIdx.x % (S/4))*4 + (threadIdx.x >> 6);
    int lane = threadIdx.x & 63;
    const float* ep = enc + ((long)b*S + s)*H + lane*8;
    f32x4 e0 = *(const f32x4*)(ep);
    f32x4 e1 = *(const f32x4*)(ep + 4);
    const float* hwp = hw + b*H + lane*8;
    f32x4 h0 = *(const f32x4*)(hwp);
    f32x4 h1 = *(const f32x4*)(hwp + 4);
    float acc = 0.f;
    #pragma unroll
    for (int m = 0; m < 4; m++) acc += h0[m]*e0[m] + h1[m]*e1[m];
    for (int off = 32; off > 0; off >>= 1) acc += __shfl_xor(acc, off);
    if (lane == 0){
        attd[b*S + s] = acc;
        out[O_NPA + ((long)b*(T+1) + T)*S + s] = acc;
    }
}

// ---------------- K3: temporal denominator ----------------
__global__ void k_denom(const float* pa, float* den){
    int i = blockIdx.x*256 + threadIdx.x;   // B*S
    int b = i / S, s = i % S;
    float sum = 0.f;
    for (int t = 0; t < T; t++)
        sum += expf(pa[((long)b*T + t)*S + s]);
    den[i] = sum;
}

// ---------------- K4: att normalize ----------------
__global__ void k_attnorm(const float* attd, const float* den,
                          float* att, float* out){
    int b = blockIdx.x, tid = threadIdx.x;
    __shared__ float tmp[S];
    __shared__ float red[256];
    float part = 0.f;
    for (int s = tid; s < S; s += 256){
        float e = expf(attd[b*S + s]) / den[b*S + s];
        tmp[s] = e; part += e;
    }
    red[tid] = part; __syncthreads();
    for (int off = 128; off > 0; off >>= 1){
        if (tid < off) red[tid] += red[tid + off];
        __syncthreads();
    }
    float inv = 1.f / red[0];
    for (int s = tid; s < S; s += 256){
        float a = tmp[s] * inv;
        att[b*S + s] = a;
        out[O_ATT + b*S + s] = a;
    }
}

// ---------------- K5: enc_ctx partials (4 s-chunks) ----------------
__global__ void k_encctx(const float* att, const float* enc, float* encp){
    int b = blockIdx.x >> 2, c = blockIdx.x & 3;
    int k = threadIdx.x;  // 512 threads
    float acc = 0.f;
    for (int i = 0; i < S/4; i++){
        int s = c*(S/4) + i;
        acc += att[b*S + s] * enc[((long)b*S + s)*H + k];
    }
    encp[(b*4 + c)*H + k] = acc;
}

// ---------------- K6: decoder self-attention ----------------
__global__ void k_dec(const float* hwd, const float* pdh, float* dec){
    int b = blockIdx.x;
    int wave = threadIdx.x >> 6, lane = threadIdx.x & 63;
    __shared__ float sc[T];
    for (int t = wave; t < T; t += 4){
        const float* pp = pdh + ((long)b*T + t)*H + lane*8;
        f32x4 p0 = *(const f32x4*)(pp);
        f32x4 p1 = *(const f32x4*)(pp + 4);
        const float* hp = hwd + b*H + lane*8;
        f32x4 h0 = *(const f32x4*)(hp);
        f32x4 h1 = *(const f32x4*)(hp + 4);
        float acc = 0.f;
        #pragma unroll
        for (int m = 0; m < 4; m++) acc += h0[m]*p0[m] + h1[m]*p1[m];
        for (int off = 32; off > 0; off >>= 1) acc += __shfl_xor(acc, off);
        if (lane == 0) sc[t] = acc;
    }
    __syncthreads();
    if (wave == 0){
        float xv = (lane < T) ? sc[lane] : -1e30f;
        float m = xv;
        for (int off = 32; off > 0; off >>= 1) m = fmaxf(m, __shfl_xor(m, off));
        float e = (lane < T) ? expf(xv - m) : 0.f;
        float ssum = e;
        for (int off = 32; off > 0; off >>= 1) ssum += __shfl_xor(ssum, off);
        if (lane < T) sc[lane] = e / ssum;
    }
    __syncthreads();
    for (int k = threadIdx.x; k < H; k += 256){
        float acc = 0.f;
        for (int t = 0; t < T; t++)
            acc += sc[t] * pdh[((long)b*T + t)*H + k];
        dec[b*H + k] = acc;
    }
}

// ---------------- K7: combined -> projbf (bf16, for MFMA) + p_gen ----------------
__global__ void k_proj(const float* h, const float* encp, const float* dec,
                       const float* Woh, const float* boh,
                       const float* Wgen, const float* bgen,
                       short* projbf, float* pg, float* out){
    int b = blockIdx.x, tid = threadIdx.x;
    __shared__ float comb[G3];
    for (int j = tid; j < G3; j += 256){
        float v;
        if (j < H) v = h[b*H + j];
        else if (j < 2*H){
            int k = j - H;
            v = encp[(b*4+0)*H+k] + encp[(b*4+1)*H+k] + encp[(b*4+2)*H+k] + encp[(b*4+3)*H+k];
        } else v = dec[b*H + (j - 2*H)];
        comb[j] = v;
    }
    __syncthreads();
    int wave = tid >> 6, lane = tid & 63;
    for (int e = wave; e < E; e += 4){
        float acc = 0.f;
        #pragma unroll
        for (int m = 0; m < 24; m++)
            acc += comb[lane + 64*m] * Woh[(long)e*G3 + lane + 64*m];
        for (int off = 32; off > 0; off >>= 1) acc += __shfl_xor(acc, off);
        if (lane == 0)
            projbf[b*E + e] = f2bs(acc + boh[e]);
    }
    if (wave == 0){
        float acc = 0.f;
        #pragma unroll
        for (int m = 0; m < 24; m++)
            acc += comb[lane + 64*m] * Wgen[lane + 64*m];
        for (int off = 32; off > 0; off >>= 1) acc += __shfl_xor(acc, off);
        if (lane == 0){
            float pv = sigmoidf_(acc + bgen[0]);
            pg[b] = pv;
            out[O_PGEN + b] = pv;
        }
    }
}

// ---------------- K9: logits (MFMA, inline f32->bf16 on W_ov) -> f32 p_vocab region ----------------
// grid = V/16 blocks, 256 thr (4 waves); wave w handles batch-tile [16w,16w+16)
__global__ void k_logits(const short* projbf, const float* Wov,
                         const float* bov, float* out){
    int wv = threadIdx.x >> 6, lane = threadIdx.x & 63;
    int btile = wv * 16;
    int vbase = blockIdx.x * 16;
    int row = lane & 15, kg = lane >> 4;
    f32x4 acc = {0.f, 0.f, 0.f, 0.f};
    const short* Ap = projbf + (btile + row)*E + kg*8;
    const float* Bp = Wov + ((long)(vbase + row))*E + kg*8;
    #pragma unroll
    for (int ks = 0; ks < 8; ks++){
        short8 a = *(const short8*)(Ap + ks*32);
        f32x4 w0 = *(const f32x4*)(Bp + ks*32);
        f32x4 w1 = *(const f32x4*)(Bp + ks*32 + 4);
        short8 bb;
        bb[0]=f2bs(w0[0]); bb[1]=f2bs(w0[1]); bb[2]=f2bs(w0[2]); bb[3]=f2bs(w0[3]);
        bb[4]=f2bs(w1[0]); bb[5]=f2bs(w1[1]); bb[6]=f2bs(w1[2]); bb[7]=f2bs(w1[3]);
        acc = __builtin_amdgcn_mfma_f32_16x16x32_bf16(a, bb, acc, 0, 0, 0);
    }
    int v = vbase + row;
    float bv = bov[v];
    #pragma unroll
    for (int r = 0; r < 4; r++){
        int bg = btile + kg*4 + r;   // C/D: col=lane&15 (v), row=(lane>>4)*4+r (batch)
        out[O_PVOCAB + (long)bg*V + v] = acc[r] + bv;
    }
}

// ---------------- K10: per-row online softmax reduce ----------------
__global__ void k_smreduce(const float* logits, float* maxv, float* sumv){
    int b = blockIdx.x, tid = threadIdx.x;
    float m = -1e30f, s = 0.f;
    for (int v = tid; v < V; v += 256){
        float x = logits[(long)b*V + v];
        if (x > m){ s = s*expf(m - x) + 1.f; m = x; }
        else s += expf(x - m);
    }
    __shared__ float ms[256], ss[256];
    ms[tid] = m; ss[tid] = s; __syncthreads();
    for (int off = 128; off > 0; off >>= 1){
        if (tid < off){
            float m1 = ms[tid], m2 = ms[tid+off], s1 = ss[tid], s2 = ss[tid+off];
            float mm = fmaxf(m1, m2);
            ms[tid] = mm; ss[tid] = s1*expf(m1 - mm) + s2*expf(m2 - mm);
        }
        __syncthreads();
    }
    if (tid == 0){ maxv[b] = ms[0]; sumv[b] = ss[0]; }
}

// ---------------- K11: p_vocab (in place) + p_final base = pv*g ----------------
__global__ void k_final(const float* maxv, const float* sumv,
                        const float* pg, float* out){
    int t = blockIdx.x*256 + threadIdx.x;
    int b = blockIdx.y;
    if (t >= EXT) return;
    float g = pg[b];
    float pf;
    if (t < V){
        long idx = O_PVOCAB + (long)b*V + t;
        float lg = out[idx];
        float pv = expf(lg - maxv[b]) / sumv[b];
        out[idx] = pv;
        pf = pv*g;
    } else {
        pf = 0.f;
    }
    out[O_PFINAL + (long)b*EXT + t] = pf;
}

// ---------------- K11b: scatter-add (1-g)*att into p_final ----------------
__global__ void k_scatter(const int* fiv, const float* att, const float* pg,
                          float* out){
    int i = blockIdx.x*256 + threadIdx.x;   // B*S
    int b = i / S;
    float val = (1.f - pg[b]) * att[i];
    atomicAdd(&out[O_PFINAL + (long)b*EXT + fiv[i]], val);
}

// ---------------- K12: concat copies (float4) ----------------
__global__ void k_copies(const float* pdh, const float* pa, float* out){
    const long n1 = (long)B*T*H/4, n2 = (long)B*T*S/4;
    long i = (long)blockIdx.x*256 + threadIdx.x;
    long stride = (long)gridDim.x*256;
    for (; i < n1 + n2; i += stride){
        if (i < n1){
            long idx = i*4;
            int b = (int)(idx/(T*H)); int r = (int)(idx%(T*H)); int t = r/H; int k = r%H;
            *(f32x4*)(out + O_DECH + ((long)b*(T+1) + t)*H + k) = *(const f32x4*)(pdh + idx);
        } else {
            long idx = (i - n1)*4;
            int b = (int)(idx/(T*S)); int r = (int)(idx%(T*S)); int t = r/S; int s = r%S;
            *(f32x4*)(out + O_NPA + ((long)b*(T+1) + t)*S + s) = *(const f32x4*)(pa + idx);
        }
    }
}

extern "C" void kernel_launch(void* const* d_in, const int* in_sizes, int n_in,
                              void* d_out, int out_size, void* d_ws, size_t ws_size,
                              hipStream_t stream) {
    const int*   tok  = (const int*)d_in[0];
    const float* pdh  = (const float*)d_in[1];
    const float* lh   = (const float*)d_in[2];
    const float* enc  = (const float*)d_in[3];
    const int*   fiv  = (const int*)d_in[4];
    const float* pa   = (const float*)d_in[5];
    // d_in[6] = nb_unk_tokens (scalar, = 50)
    const float* emb  = (const float*)d_in[7];
    const float* Wih  = (const float*)d_in[8];
    const float* Whh  = (const float*)d_in[9];
    const float* bih  = (const float*)d_in[10];
    const float* bhh  = (const float*)d_in[11];
    const float* wh   = (const float*)d_in[12];
    const float* wd   = (const float*)d_in[13];
    const float* Woh  = (const float*)d_in[14];
    const float* boh  = (const float*)d_in[15];
    const float* Wov  = (const float*)d_in[16];
    const float* bov  = (const float*)d_in[17];
    const float* Wgen = (const float*)d_in[18];
    const float* bgen = (const float*)d_in[19];

    float* ws  = (float*)d_ws;
    float* out = (float*)d_out;

    float* x      = ws + OFF_X;
    float* g      = ws + OFF_G;
    float* Gg     = ws + OFF_GG;
    float* h      = ws + OFF_H;
    float* hw     = ws + OFF_HW;
    float* hwd    = ws + OFF_HWD;
    float* attd   = ws + OFF_ATTD;
    float* den    = ws + OFF_DEN;
    float* encp   = ws + OFF_ENCP;
    float* dec    = ws + OFF_DEC;
    float* att    = ws + OFF_ATT;
    float* pg     = ws + OFF_PG;
    float* maxv   = ws + OFF_MAX;
    float* sumv   = ws + OFF_SUM;
    short* projbf = (short*)(ws + OFF_PROJBF);

    k_embed  <<<(B*E)/256, 256, 0, stream>>>(tok, emb, x);
    k_gates  <<<B*384, 256, 0, stream>>>(x, lh, Wih, Whh, bih, bhh, g, Gg);
    k_gru    <<<(B*H)/256, 256, 0, stream>>>(g, Gg, lh, wh, wd, h, hw, hwd, out);
    k_attdist<<<B*(S/4), 256, 0, stream>>>(hw, enc, attd, out);
    k_denom  <<<(B*S)/256, 256, 0, stream>>>(pa, den);
    k_attnorm<<<B, 256, 0, stream>>>(attd, den, att, out);
    k_encctx <<<B*4, 512, 0, stream>>>(att, enc, encp);
    k_dec    <<<B, 256, 0, stream>>>(hwd, pdh, dec);
    k_proj   <<<B, 256, 0, stream>>>(h, encp, dec, Woh, boh, Wgen, bgen,
                                     projbf, pg, out);
    k_logits <<<V/16, 256, 0, stream>>>(projbf, Wov, bov, out);
    k_smreduce<<<B, 256, 0, stream>>>(out + O_PVOCAB, maxv, sumv);
    {
        dim3 grid((EXT + 255)/256, B);
        k_final<<<grid, 256, 0, stream>>>(maxv, sumv, pg, out);
    }
    k_scatter<<<(B*S)/256, 256, 0, stream>>>(fiv, att, pg, out);
    k_copies <<<2850, 256, 0, stream>>>(pdh, pa, out);
}

// Round 5
// 187.672 us; speedup vs baseline: 1.3238x; 1.3238x over previous
//
#include <hip/hip_runtime.h>
#include <hip/hip_bf16.h>

#define B 64
#define T 50
#define S 400
#define H 512
#define E 256
#define V 50000
#define EXT 50250
#define G3 1536
#define NCH 32

typedef __attribute__((ext_vector_type(8))) short short8;
typedef __attribute__((ext_vector_type(4))) float f32x4;

// ---- output offsets (f32 elements, return order) ----
#define O_PFINAL 0L
#define O_PGEN   3216000L
#define O_PVOCAB 3216064L
#define O_ATT    6416064L
#define O_DECH   6441664L
#define O_H      8112832L
#define O_NPA    8145600L

// ---- workspace offsets (f32 elements); total ~568K f32 = 2.27 MB ----
#define OFF_X      0L        /* B*E   */
#define OFF_G      16384L    /* B*G3  */
#define OFF_GG     114688L   /* B*G3  */
#define OFF_H      212992L   /* B*H   */
#define OFF_HW     245760L   /* B*H   */
#define OFF_HWD    278528L   /* B*H   */
#define OFF_ATTD   311296L   /* B*S   */
#define OFF_DEN    336896L   /* B*S   */
#define OFF_ENCP   362496L   /* B*4*H */
#define OFF_DEC    493568L   /* B*H   */
#define OFF_ATT    526336L   /* B*S   */
#define OFF_PG     551936L   /* 64 */
#define OFF_MAX    552000L   /* 64 */
#define OFF_SUM    552064L   /* 64 */
#define OFF_PROJBF 552128L   /* 16384 bf16 = 8192 f32 slots */
#define OFF_PMAX   560320L   /* B*NCH = 2048 */
#define OFF_PSUM   562368L   /* B*NCH = 2048 */
#define OFF_SC     564416L   /* B*T   = 3200 -> end 567616 */

__device__ __forceinline__ float sigmoidf_(float x){ return 1.0f/(1.0f+expf(-x)); }
__device__ __forceinline__ short f2bs(float x){
    union { __hip_bfloat16 b; short s; } c; c.b = __float2bfloat16(x); return c.s;
}

// ---------------- K1a: embedding gather ----------------
__global__ void k_embed(const int* tok, const float* emb, float* x){
    int i = blockIdx.x*256 + threadIdx.x;   // B*E
    int b = i >> 8, e = i & 255;
    x[i] = emb[(long)tok[b]*E + e];
}

// ---------------- K1b: GRU gate pre-activations ----------------
__global__ void k_gates(const float* x, const float* lh,
                        const float* Wih, const float* Whh,
                        const float* bih, const float* bhh,
                        float* g, float* Gg){
    int blk = blockIdx.x;
    int b = blk / 384, jg = blk % 384;
    int wave = threadIdx.x >> 6, lane = threadIdx.x & 63;
    int j = jg*4 + wave;
    const float* xb = x + b*E;
    float gi = 0.f, gh = 0.f;
    #pragma unroll
    for (int m = 0; m < 4; m++)
        gi += xb[lane + 64*m] * Wih[(long)j*E + lane + 64*m];
    #pragma unroll
    for (int m = 0; m < 8; m++)
        gh += lh[b*H + lane + 64*m] * Whh[(long)j*H + lane + 64*m];
    for (int off = 32; off > 0; off >>= 1){
        gi += __shfl_xor(gi, off);
        gh += __shfl_xor(gh, off);
    }
    if (lane == 0){
        g [b*G3 + j] = gi + bih[j];
        Gg[b*G3 + j] = gh + bhh[j];
    }
}

// ---------------- K1c: GRU combine -> h, hw, hwd ----------------
__global__ void k_gru(const float* g, const float* Gg, const float* lh,
                      const float* wh, const float* wd,
                      float* h, float* hw, float* hwd, float* out){
    int i = blockIdx.x*256 + threadIdx.x;   // B*H
    int b = i >> 9, k = i & 511;
    float ir = g [b*G3 + k], iz = g [b*G3 + H + k], inn = g [b*G3 + 2*H + k];
    float hr = Gg[b*G3 + k], hz = Gg[b*G3 + H + k], hn  = Gg[b*G3 + 2*H + k];
    float r = sigmoidf_(ir + hr), z = sigmoidf_(iz + hz);
    float n = tanhf(inn + r*hn);
    float hp = lh[i];
    float hv = (1.f - z)*n + z*hp;
    h[i] = hv; hw[i] = hv * wh[k]; hwd[i] = hv * wd[k];
    out[O_H + i] = hv;
    out[O_DECH + ((long)b*(T+1) + T)*H + k] = hv;
}

// ---------------- K2: att_dist = h . (w_h * enc) ----------------
__global__ void k_attdist(const float* hw, const float* enc,
                          float* attd, float* out){
    int b = blockIdx.x / (S/4);
    int s = (blockIdx.x % (S/4))*4 + (threadIdx.x >> 6);
    int lane = threadIdx.x & 63;
    const float* ep = enc + ((long)b*S + s)*H + lane*8;
    f32x4 e0 = *(const f32x4*)(ep);
    f32x4 e1 = *(const f32x4*)(ep + 4);
    const float* hwp = hw + b*H + lane*8;
    f32x4 h0 = *(const f32x4*)(hwp);
    f32x4 h1 = *(const f32x4*)(hwp + 4);
    float acc = 0.f;
    #pragma unroll
    for (int m = 0; m < 4; m++) acc += h0[m]*e0[m] + h1[m]*e1[m];
    for (int off = 32; off > 0; off >>= 1) acc += __shfl_xor(acc, off);
    if (lane == 0){
        attd[b*S + s] = acc;
        out[O_NPA + ((long)b*(T+1) + T)*S + s] = acc;
    }
}

// ---------------- K3: temporal denominator ----------------
__global__ void k_denom(const float* pa, float* den){
    int i = blockIdx.x*256 + threadIdx.x;   // B*S
    int b = i / S, s = i % S;
    float sum = 0.f;
    for (int t = 0; t < T; t++)
        sum += expf(pa[((long)b*T + t)*S + s]);
    den[i] = sum;
}

// ---------------- K4: att normalize ----------------
__global__ void k_attnorm(const float* attd, const float* den,
                          float* att, float* out){
    int b = blockIdx.x, tid = threadIdx.x;
    __shared__ float tmp[S];
    __shared__ float red[256];
    float part = 0.f;
    for (int s = tid; s < S; s += 256){
        float e = expf(attd[b*S + s]) / den[b*S + s];
        tmp[s] = e; part += e;
    }
    red[tid] = part; __syncthreads();
    for (int off = 128; off > 0; off >>= 1){
        if (tid < off) red[tid] += red[tid + off];
        __syncthreads();
    }
    float inv = 1.f / red[0];
    for (int s = tid; s < S; s += 256){
        float a = tmp[s] * inv;
        att[b*S + s] = a;
        out[O_ATT + b*S + s] = a;
    }
}

// ---------------- K5: enc_ctx partials (4 s-chunks) ----------------
__global__ void k_encctx(const float* att, const float* enc, float* encp){
    int b = blockIdx.x >> 2, c = blockIdx.x & 3;
    int k = threadIdx.x;  // 512 threads
    float acc = 0.f;
    for (int i = 0; i < S/4; i++){
        int s = c*(S/4) + i;
        acc += att[b*S + s] * enc[((long)b*S + s)*H + k];
    }
    encp[(b*4 + c)*H + k] = acc;
}

// ---------------- K6a: decoder scores + softmax -> sc ----------------
__global__ void k_decsc(const float* hwd, const float* pdh, float* sc){
    int b = blockIdx.x;
    int wave = threadIdx.x >> 6, lane = threadIdx.x & 63;
    __shared__ float scs[T];
    for (int t = wave; t < T; t += 4){
        const float* pp = pdh + ((long)b*T + t)*H + lane*8;
        f32x4 p0 = *(const f32x4*)(pp);
        f32x4 p1 = *(const f32x4*)(pp + 4);
        const float* hp = hwd + b*H + lane*8;
        f32x4 h0 = *(const f32x4*)(hp);
        f32x4 h1 = *(const f32x4*)(hp + 4);
        float acc = 0.f;
        #pragma unroll
        for (int m = 0; m < 4; m++) acc += h0[m]*p0[m] + h1[m]*p1[m];
        for (int off = 32; off > 0; off >>= 1) acc += __shfl_xor(acc, off);
        if (lane == 0) scs[t] = acc;
    }
    __syncthreads();
    if (wave == 0){
        float xv = (lane < T) ? scs[lane] : -1e30f;
        float m = xv;
        for (int off = 32; off > 0; off >>= 1) m = fmaxf(m, __shfl_xor(m, off));
        float e = (lane < T) ? expf(xv - m) : 0.f;
        float ssum = e;
        for (int off = 32; off > 0; off >>= 1) ssum += __shfl_xor(ssum, off);
        if (lane < T) sc[b*T + lane] = e / ssum;
    }
}

// ---------------- K6b: decoder context (B*4 blocks, 128 thr) ----------------
__global__ void k_decctx(const float* sc, const float* pdh, float* dec){
    int b = blockIdx.x >> 2, c = blockIdx.x & 3;
    int k = c*128 + threadIdx.x;
    float acc = 0.f;
    for (int t = 0; t < T; t++)
        acc += sc[b*T + t] * pdh[((long)b*T + t)*H + k];
    dec[b*H + k] = acc;
}

// ---------------- K7: combined -> projbf (bf16, for MFMA) + p_gen ----------------
__global__ void k_proj(const float* h, const float* encp, const float* dec,
                       const float* Woh, const float* boh,
                       const float* Wgen, const float* bgen,
                       short* projbf, float* pg, float* out){
    int b = blockIdx.x, tid = threadIdx.x;
    __shared__ float comb[G3];
    for (int j = tid; j < G3; j += 256){
        float v;
        if (j < H) v = h[b*H + j];
        else if (j < 2*H){
            int k = j - H;
            v = encp[(b*4+0)*H+k] + encp[(b*4+1)*H+k] + encp[(b*4+2)*H+k] + encp[(b*4+3)*H+k];
        } else v = dec[b*H + (j - 2*H)];
        comb[j] = v;
    }
    __syncthreads();
    int wave = tid >> 6, lane = tid & 63;
    for (int e = wave; e < E; e += 4){
        float acc = 0.f;
        #pragma unroll
        for (int m = 0; m < 24; m++)
            acc += comb[lane + 64*m] * Woh[(long)e*G3 + lane + 64*m];
        for (int off = 32; off > 0; off >>= 1) acc += __shfl_xor(acc, off);
        if (lane == 0)
            projbf[b*E + e] = f2bs(acc + boh[e]);
    }
    if (wave == 0){
        float acc = 0.f;
        #pragma unroll
        for (int m = 0; m < 24; m++)
            acc += comb[lane + 64*m] * Wgen[lane + 64*m];
        for (int off = 32; off > 0; off >>= 1) acc += __shfl_xor(acc, off);
        if (lane == 0){
            float pv = sigmoidf_(acc + bgen[0]);
            pg[b] = pv;
            out[O_PGEN + b] = pv;
        }
    }
}

// ---------------- K9: logits (MFMA, inline f32->bf16 on W_ov) ----------------
__global__ void k_logits(const short* projbf, const float* Wov,
                         const float* bov, float* out){
    int wv = threadIdx.x >> 6, lane = threadIdx.x & 63;
    int btile = wv * 16;
    int vbase = blockIdx.x * 16;
    int row = lane & 15, kg = lane >> 4;
    f32x4 acc = {0.f, 0.f, 0.f, 0.f};
    const short* Ap = projbf + (btile + row)*E + kg*8;
    const float* Bp = Wov + ((long)(vbase + row))*E + kg*8;
    #pragma unroll
    for (int ks = 0; ks < 8; ks++){
        short8 a = *(const short8*)(Ap + ks*32);
        f32x4 w0 = *(const f32x4*)(Bp + ks*32);
        f32x4 w1 = *(const f32x4*)(Bp + ks*32 + 4);
        short8 bb;
        bb[0]=f2bs(w0[0]); bb[1]=f2bs(w0[1]); bb[2]=f2bs(w0[2]); bb[3]=f2bs(w0[3]);
        bb[4]=f2bs(w1[0]); bb[5]=f2bs(w1[1]); bb[6]=f2bs(w1[2]); bb[7]=f2bs(w1[3]);
        acc = __builtin_amdgcn_mfma_f32_16x16x32_bf16(a, bb, acc, 0, 0, 0);
    }
    int v = vbase + row;
    float bv = bov[v];
    #pragma unroll
    for (int r = 0; r < 4; r++){
        int bg = btile + kg*4 + r;
        out[O_PVOCAB + (long)bg*V + v] = acc[r] + bv;
    }
}

// ---------------- K10a: partial online softmax (B*NCH blocks) ----------------
__global__ void k_smpart(const float* logits, float* pmax, float* psum){
    int b = blockIdx.x / NCH, c = blockIdx.x % NCH;
    const int chunk = (V + NCH - 1)/NCH;   // 1563
    int start = c*chunk;
    int end = start + chunk; if (end > V) end = V;
    float m = -1e30f, s = 0.f;
    for (int v = start + threadIdx.x; v < end; v += 256){
        float x = logits[(long)b*V + v];
        if (x > m){ s = s*expf(m - x) + 1.f; m = x; }
        else s += expf(x - m);
    }
    __shared__ float ms[256], ss[256];
    int tid = threadIdx.x;
    ms[tid] = m; ss[tid] = s; __syncthreads();
    for (int off = 128; off > 0; off >>= 1){
        if (tid < off){
            float m1 = ms[tid], m2 = ms[tid+off], s1 = ss[tid], s2 = ss[tid+off];
            float mm = fmaxf(m1, m2);
            ms[tid] = mm; ss[tid] = s1*expf(m1 - mm) + s2*expf(m2 - mm);
        }
        __syncthreads();
    }
    if (tid == 0){ pmax[blockIdx.x] = ms[0]; psum[blockIdx.x] = ss[0]; }
}

// ---------------- K10b: combine partials (B blocks, 1 wave) ----------------
__global__ void k_smcomb(const float* pmax, const float* psum,
                         float* maxv, float* sumv){
    int b = blockIdx.x, lane = threadIdx.x;  // 64 threads
    float m = (lane < NCH) ? pmax[b*NCH + lane] : -1e30f;
    float s = (lane < NCH) ? psum[b*NCH + lane] : 0.f;
    for (int off = 32; off > 0; off >>= 1){
        float m2 = __shfl_xor(m, off), s2 = __shfl_xor(s, off);
        float mm = fmaxf(m, m2);
        s = s*expf(m - mm) + s2*expf(m2 - mm);
        m = mm;
    }
    if (lane == 0){ maxv[b] = m; sumv[b] = s; }
}

// ---------------- K11: p_vocab (in place) + p_final base = pv*g ----------------
__global__ void k_final(const float* maxv, const float* sumv,
                        const float* pg, float* out){
    int t = blockIdx.x*256 + threadIdx.x;
    int b = blockIdx.y;
    if (t >= EXT) return;
    float g = pg[b];
    float pf;
    if (t < V){
        long idx = O_PVOCAB + (long)b*V + t;
        float lg = out[idx];
        float pv = expf(lg - maxv[b]) / sumv[b];
        out[idx] = pv;
        pf = pv*g;
    } else {
        pf = 0.f;
    }
    out[O_PFINAL + (long)b*EXT + t] = pf;
}

// ---------------- K11b: scatter-add (1-g)*att into p_final ----------------
__global__ void k_scatter(const int* fiv, const float* att, const float* pg,
                          float* out){
    int i = blockIdx.x*256 + threadIdx.x;   // B*S
    int b = i / S;
    float val = (1.f - pg[b]) * att[i];
    atomicAdd(&out[O_PFINAL + (long)b*EXT + fiv[i]], val);
}

// ---------------- K12: concat copies (float4) ----------------
__global__ void k_copies(const float* pdh, const float* pa, float* out){
    const long n1 = (long)B*T*H/4, n2 = (long)B*T*S/4;
    long i = (long)blockIdx.x*256 + threadIdx.x;
    long stride = (long)gridDim.x*256;
    for (; i < n1 + n2; i += stride){
        if (i < n1){
            long idx = i*4;
            int b = (int)(idx/(T*H)); int r = (int)(idx%(T*H)); int t = r/H; int k = r%H;
            *(f32x4*)(out + O_DECH + ((long)b*(T+1) + t)*H + k) = *(const f32x4*)(pdh + idx);
        } else {
            long idx = (i - n1)*4;
            int b = (int)(idx/(T*S)); int r = (int)(idx%(T*S)); int t = r/S; int s = r%S;
            *(f32x4*)(out + O_NPA + ((long)b*(T+1) + t)*S + s) = *(const f32x4*)(pa + idx);
        }
    }
}

extern "C" void kernel_launch(void* const* d_in, const int* in_sizes, int n_in,
                              void* d_out, int out_size, void* d_ws, size_t ws_size,
                              hipStream_t stream) {
    const int*   tok  = (const int*)d_in[0];
    const float* pdh  = (const float*)d_in[1];
    const float* lh   = (const float*)d_in[2];
    const float* enc  = (const float*)d_in[3];
    const int*   fiv  = (const int*)d_in[4];
    const float* pa   = (const float*)d_in[5];
    const float* emb  = (const float*)d_in[7];
    const float* Wih  = (const float*)d_in[8];
    const float* Whh  = (const float*)d_in[9];
    const float* bih  = (const float*)d_in[10];
    const float* bhh  = (const float*)d_in[11];
    const float* wh   = (const float*)d_in[12];
    const float* wd   = (const float*)d_in[13];
    const float* Woh  = (const float*)d_in[14];
    const float* boh  = (const float*)d_in[15];
    const float* Wov  = (const float*)d_in[16];
    const float* bov  = (const float*)d_in[17];
    const float* Wgen = (const float*)d_in[18];
    const float* bgen = (const float*)d_in[19];

    float* ws  = (float*)d_ws;
    float* out = (float*)d_out;

    float* x      = ws + OFF_X;
    float* g      = ws + OFF_G;
    float* Gg     = ws + OFF_GG;
    float* h      = ws + OFF_H;
    float* hw     = ws + OFF_HW;
    float* hwd    = ws + OFF_HWD;
    float* attd   = ws + OFF_ATTD;
    float* den    = ws + OFF_DEN;
    float* encp   = ws + OFF_ENCP;
    float* dec    = ws + OFF_DEC;
    float* att    = ws + OFF_ATT;
    float* pg     = ws + OFF_PG;
    float* maxv   = ws + OFF_MAX;
    float* sumv   = ws + OFF_SUM;
    short* projbf = (short*)(ws + OFF_PROJBF);
    float* pmax   = ws + OFF_PMAX;
    float* psum   = ws + OFF_PSUM;
    float* sc     = ws + OFF_SC;

    k_embed  <<<(B*E)/256, 256, 0, stream>>>(tok, emb, x);
    k_gates  <<<B*384, 256, 0, stream>>>(x, lh, Wih, Whh, bih, bhh, g, Gg);
    k_gru    <<<(B*H)/256, 256, 0, stream>>>(g, Gg, lh, wh, wd, h, hw, hwd, out);
    k_attdist<<<B*(S/4), 256, 0, stream>>>(hw, enc, attd, out);
    k_denom  <<<(B*S)/256, 256, 0, stream>>>(pa, den);
    k_attnorm<<<B, 256, 0, stream>>>(attd, den, att, out);
    k_encctx <<<B*4, 512, 0, stream>>>(att, enc, encp);
    k_decsc  <<<B, 256, 0, stream>>>(hwd, pdh, sc);
    k_decctx <<<B*4, 128, 0, stream>>>(sc, pdh, dec);
    k_proj   <<<B, 256, 0, stream>>>(h, encp, dec, Woh, boh, Wgen, bgen,
                                     projbf, pg, out);
    k_logits <<<V/16, 256, 0, stream>>>(projbf, Wov, bov, out);
    k_smpart <<<B*NCH, 256, 0, stream>>>(out + O_PVOCAB, pmax, psum);
    k_smcomb <<<B, 64, 0, stream>>>(pmax, psum, maxv, sumv);
    {
        dim3 grid((EXT + 255)/256, B);
        k_final<<<grid, 256, 0, stream>>>(maxv, sumv, pg, out);
    }
    k_scatter<<<(B*S)/256, 256, 0, stream>>>(fiv, att, pg, out);
    k_copies <<<2850, 256, 0, stream>>>(pdh, pa, out);
}

// Round 6
// 148.941 us; speedup vs baseline: 1.6681x; 1.2600x over previous
//
#include <hip/hip_runtime.h>
#include <hip/hip_bf16.h>

#define B 64
#define T 50
#define S 400
#define H 512
#define E 256
#define V 50000
#define EXT 50250
#define G3 1536
#define NCH 32

typedef __attribute__((ext_vector_type(8))) short short8;
typedef __attribute__((ext_vector_type(4))) float f32x4;

// ---- output offsets (f32 elements, return order) ----
#define O_PFINAL 0L
#define O_PGEN   3216000L
#define O_PVOCAB 3216064L
#define O_ATT    6416064L
#define O_DECH   6441664L
#define O_H      8112832L
#define O_NPA    8145600L

// ---- workspace offsets (f32 elements); total ~568K f32 = 2.27 MB ----
#define OFF_X      0L        /* B*E   */
#define OFF_G      16384L    /* B*G3 ; DEAD after k_gru -> comb overlays */
#define OFF_GG     114688L   /* B*G3  */
#define OFF_H      212992L   /* B*H   */
#define OFF_HW     245760L   /* B*H   */
#define OFF_HWD    278528L   /* B*H   */
#define OFF_ATTD   311296L   /* B*S   */
#define OFF_DEN    336896L   /* B*S   */
#define OFF_ENCP   362496L   /* B*4*H */
#define OFF_DEC    493568L   /* B*H   */
#define OFF_ATT    526336L   /* B*S   */
#define OFF_PG     551936L   /* 64 */
#define OFF_MAX    552000L   /* 64 */
#define OFF_SUM    552064L   /* 64 */
#define OFF_PROJBF 552128L   /* 16384 bf16 = 8192 f32 slots */
#define OFF_PMAX   560320L   /* B*NCH */
#define OFF_PSUM   562368L   /* B*NCH */
#define OFF_SC     564416L   /* B*T -> end 567616 */
#define OFF_COMB   OFF_G     /* B*G3 overlay */

__device__ __forceinline__ float sigmoidf_(float x){ return 1.0f/(1.0f+expf(-x)); }
__device__ __forceinline__ short f2bs(float x){
    union { __hip_bfloat16 b; short s; } c; c.b = __float2bfloat16(x); return c.s;
}

// ---------------- K1a: embedding gather ----------------
__global__ void k_embed(const int* tok, const float* emb, float* x){
    int i = blockIdx.x*256 + threadIdx.x;   // B*E
    int b = i >> 8, e = i & 255;
    x[i] = emb[(long)tok[b]*E + e];
}

// ---------------- K1b: GRU gate pre-activations ----------------
__global__ void k_gates(const float* x, const float* lh,
                        const float* Wih, const float* Whh,
                        const float* bih, const float* bhh,
                        float* g, float* Gg){
    int blk = blockIdx.x;
    int b = blk / 384, jg = blk % 384;
    int wave = threadIdx.x >> 6, lane = threadIdx.x & 63;
    int j = jg*4 + wave;
    const float* xb = x + b*E;
    float gi = 0.f, gh = 0.f;
    #pragma unroll
    for (int m = 0; m < 4; m++)
        gi += xb[lane + 64*m] * Wih[(long)j*E + lane + 64*m];
    #pragma unroll
    for (int m = 0; m < 8; m++)
        gh += lh[b*H + lane + 64*m] * Whh[(long)j*H + lane + 64*m];
    for (int off = 32; off > 0; off >>= 1){
        gi += __shfl_xor(gi, off);
        gh += __shfl_xor(gh, off);
    }
    if (lane == 0){
        g [b*G3 + j] = gi + bih[j];
        Gg[b*G3 + j] = gh + bhh[j];
    }
}

// ---------------- K1c: GRU combine -> h, hw, hwd ----------------
__global__ void k_gru(const float* g, const float* Gg, const float* lh,
                      const float* wh, const float* wd,
                      float* h, float* hw, float* hwd, float* out){
    int i = blockIdx.x*256 + threadIdx.x;   // B*H
    int b = i >> 9, k = i & 511;
    float ir = g [b*G3 + k], iz = g [b*G3 + H + k], inn = g [b*G3 + 2*H + k];
    float hr = Gg[b*G3 + k], hz = Gg[b*G3 + H + k], hn  = Gg[b*G3 + 2*H + k];
    float r = sigmoidf_(ir + hr), z = sigmoidf_(iz + hz);
    float n = tanhf(inn + r*hn);
    float hp = lh[i];
    float hv = (1.f - z)*n + z*hp;
    h[i] = hv; hw[i] = hv * wh[k]; hwd[i] = hv * wd[k];
    out[O_H + i] = hv;
    out[O_DECH + ((long)b*(T+1) + T)*H + k] = hv;
}

// ---------------- K2: att_dist = h . (w_h * enc) ----------------
__global__ void k_attdist(const float* hw, const float* enc,
                          float* attd, float* out){
    int b = blockIdx.x / (S/4);
    int s = (blockIdx.x % (S/4))*4 + (threadIdx.x >> 6);
    int lane = threadIdx.x & 63;
    const float* ep = enc + ((long)b*S + s)*H + lane*8;
    f32x4 e0 = *(const f32x4*)(ep);
    f32x4 e1 = *(const f32x4*)(ep + 4);
    const float* hwp = hw + b*H + lane*8;
    f32x4 h0 = *(const f32x4*)(hwp);
    f32x4 h1 = *(const f32x4*)(hwp + 4);
    float acc = 0.f;
    #pragma unroll
    for (int m = 0; m < 4; m++) acc += h0[m]*e0[m] + h1[m]*e1[m];
    for (int off = 32; off > 0; off >>= 1) acc += __shfl_xor(acc, off);
    if (lane == 0){
        attd[b*S + s] = acc;
        out[O_NPA + ((long)b*(T+1) + T)*S + s] = acc;
    }
}

// ---------------- K3: temporal denominator ----------------
__global__ void k_denom(const float* pa, float* den){
    int i = blockIdx.x*256 + threadIdx.x;   // B*S
    int b = i / S, s = i % S;
    float sum = 0.f;
    for (int t = 0; t < T; t++)
        sum += expf(pa[((long)b*T + t)*S + s]);
    den[i] = sum;
}

// ---------------- K4: att normalize ----------------
__global__ void k_attnorm(const float* attd, const float* den,
                          float* att, float* out){
    int b = blockIdx.x, tid = threadIdx.x;
    __shared__ float tmp[S];
    __shared__ float red[256];
    float part = 0.f;
    for (int s = tid; s < S; s += 256){
        float e = expf(attd[b*S + s]) / den[b*S + s];
        tmp[s] = e; part += e;
    }
    red[tid] = part; __syncthreads();
    for (int off = 128; off > 0; off >>= 1){
        if (tid < off) red[tid] += red[tid + off];
        __syncthreads();
    }
    float inv = 1.f / red[0];
    for (int s = tid; s < S; s += 256){
        float a = tmp[s] * inv;
        att[b*S + s] = a;
        out[O_ATT + b*S + s] = a;
    }
}

// ---------------- K5: enc_ctx partials (4 s-chunks) ----------------
__global__ void k_encctx(const float* att, const float* enc, float* encp){
    int b = blockIdx.x >> 2, c = blockIdx.x & 3;
    int k = threadIdx.x;  // 512 threads
    float acc = 0.f;
    for (int i = 0; i < S/4; i++){
        int s = c*(S/4) + i;
        acc += att[b*S + s] * enc[((long)b*S + s)*H + k];
    }
    encp[(b*4 + c)*H + k] = acc;
}

// ---------------- K6a: decoder scores + softmax -> sc ----------------
__global__ void k_decsc(const float* hwd, const float* pdh, float* sc){
    int b = blockIdx.x;
    int wave = threadIdx.x >> 6, lane = threadIdx.x & 63;
    __shared__ float scs[T];
    for (int t = wave; t < T; t += 4){
        const float* pp = pdh + ((long)b*T + t)*H + lane*8;
        f32x4 p0 = *(const f32x4*)(pp);
        f32x4 p1 = *(const f32x4*)(pp + 4);
        const float* hp = hwd + b*H + lane*8;
        f32x4 h0 = *(const f32x4*)(hp);
        f32x4 h1 = *(const f32x4*)(hp + 4);
        float acc = 0.f;
        #pragma unroll
        for (int m = 0; m < 4; m++) acc += h0[m]*p0[m] + h1[m]*p1[m];
        for (int off = 32; off > 0; off >>= 1) acc += __shfl_xor(acc, off);
        if (lane == 0) scs[t] = acc;
    }
    __syncthreads();
    if (wave == 0){
        float xv = (lane < T) ? scs[lane] : -1e30f;
        float m = xv;
        for (int off = 32; off > 0; off >>= 1) m = fmaxf(m, __shfl_xor(m, off));
        float e = (lane < T) ? expf(xv - m) : 0.f;
        float ssum = e;
        for (int off = 32; off > 0; off >>= 1) ssum += __shfl_xor(ssum, off);
        if (lane < T) sc[b*T + lane] = e / ssum;
    }
}

// ---------------- K6b: decoder context (B*4 blocks, 128 thr) ----------------
__global__ void k_decctx(const float* sc, const float* pdh, float* dec){
    int b = blockIdx.x >> 2, c = blockIdx.x & 3;
    int k = c*128 + threadIdx.x;
    float acc = 0.f;
    for (int t = 0; t < T; t++)
        acc += sc[b*T + t] * pdh[((long)b*T + t)*H + k];
    dec[b*H + k] = acc;
}

// ---------------- K7a: build comb[B][G3] (grid = B*6, 256 thr) ----------------
__global__ void k_comb(const float* h, const float* encp, const float* dec,
                       float* comb){
    int blk = blockIdx.x;
    int b = blk / 6, j = (blk % 6)*256 + threadIdx.x;
    float v;
    if (j < H) v = h[b*H + j];
    else if (j < 2*H){
        int k = j - H;
        v = encp[(b*4+0)*H+k] + encp[(b*4+1)*H+k] + encp[(b*4+2)*H+k] + encp[(b*4+3)*H+k];
    } else v = dec[b*H + (j - 2*H)];
    comb[b*G3 + j] = v;
}

// ---------------- K7b: proj GEMM (grid = B*(E/16), 256 thr; wave -> 4 e) ----------------
__global__ void k_projgemm(const float* comb, const float* Woh, const float* boh,
                           short* projbf){
    int blk = blockIdx.x;
    int b = blk >> 4, et = blk & 15;
    int wave = threadIdx.x >> 6, lane = threadIdx.x & 63;
    int e0 = et*16 + wave*4;
    const float* cb = comb + b*G3;
    const float* w0 = Woh + (long)(e0+0)*G3;
    const float* w1 = Woh + (long)(e0+1)*G3;
    const float* w2 = Woh + (long)(e0+2)*G3;
    const float* w3 = Woh + (long)(e0+3)*G3;
    float a0=0.f, a1=0.f, a2=0.f, a3=0.f;
    #pragma unroll
    for (int m = 0; m < 24; m++){
        int idx = lane + 64*m;
        float c = cb[idx];
        a0 += c * w0[idx]; a1 += c * w1[idx];
        a2 += c * w2[idx]; a3 += c * w3[idx];
    }
    for (int off = 32; off > 0; off >>= 1){
        a0 += __shfl_xor(a0, off); a1 += __shfl_xor(a1, off);
        a2 += __shfl_xor(a2, off); a3 += __shfl_xor(a3, off);
    }
    if (lane == 0){
        projbf[b*E + e0+0] = f2bs(a0 + boh[e0+0]);
        projbf[b*E + e0+1] = f2bs(a1 + boh[e0+1]);
        projbf[b*E + e0+2] = f2bs(a2 + boh[e0+2]);
        projbf[b*E + e0+3] = f2bs(a3 + boh[e0+3]);
    }
}

// ---------------- K7c: p_gen (grid = B, 256 thr) ----------------
__global__ void k_pgen(const float* comb, const float* Wgen, const float* bgen,
                       float* pg, float* out){
    int b = blockIdx.x, tid = threadIdx.x;
    float part = 0.f;
    for (int j = tid; j < G3; j += 256)
        part += comb[b*G3 + j] * Wgen[j];
    __shared__ float red[256];
    red[tid] = part; __syncthreads();
    for (int off = 128; off > 0; off >>= 1){
        if (tid < off) red[tid] += red[tid + off];
        __syncthreads();
    }
    if (tid == 0){
        float pv = sigmoidf_(red[0] + bgen[0]);
        pg[b] = pv;
        out[O_PGEN + b] = pv;
    }
}

// ---------------- K9: logits (MFMA, inline f32->bf16 on W_ov) ----------------
__global__ void k_logits(const short* projbf, const float* Wov,
                         const float* bov, float* out){
    int wv = threadIdx.x >> 6, lane = threadIdx.x & 63;
    int btile = wv * 16;
    int vbase = blockIdx.x * 16;
    int row = lane & 15, kg = lane >> 4;
    f32x4 acc = {0.f, 0.f, 0.f, 0.f};
    const short* Ap = projbf + (btile + row)*E + kg*8;
    const float* Bp = Wov + ((long)(vbase + row))*E + kg*8;
    #pragma unroll
    for (int ks = 0; ks < 8; ks++){
        short8 a = *(const short8*)(Ap + ks*32);
        f32x4 w0 = *(const f32x4*)(Bp + ks*32);
        f32x4 w1 = *(const f32x4*)(Bp + ks*32 + 4);
        short8 bb;
        bb[0]=f2bs(w0[0]); bb[1]=f2bs(w0[1]); bb[2]=f2bs(w0[2]); bb[3]=f2bs(w0[3]);
        bb[4]=f2bs(w1[0]); bb[5]=f2bs(w1[1]); bb[6]=f2bs(w1[2]); bb[7]=f2bs(w1[3]);
        acc = __builtin_amdgcn_mfma_f32_16x16x32_bf16(a, bb, acc, 0, 0, 0);
    }
    int v = vbase + row;
    float bv = bov[v];
    #pragma unroll
    for (int r = 0; r < 4; r++){
        int bg = btile + kg*4 + r;
        out[O_PVOCAB + (long)bg*V + v] = acc[r] + bv;
    }
}

// ---------------- K10a: partial online softmax (B*NCH blocks) ----------------
__global__ void k_smpart(const float* logits, float* pmax, float* psum){
    int b = blockIdx.x / NCH, c = blockIdx.x % NCH;
    const int chunk = (V + NCH - 1)/NCH;   // 1563
    int start = c*chunk;
    int end = start + chunk; if (end > V) end = V;
    float m = -1e30f, s = 0.f;
    for (int v = start + threadIdx.x; v < end; v += 256){
        float x = logits[(long)b*V + v];
        if (x > m){ s = s*expf(m - x) + 1.f; m = x; }
        else s += expf(x - m);
    }
    __shared__ float ms[256], ss[256];
    int tid = threadIdx.x;
    ms[tid] = m; ss[tid] = s; __syncthreads();
    for (int off = 128; off > 0; off >>= 1){
        if (tid < off){
            float m1 = ms[tid], m2 = ms[tid+off], s1 = ss[tid], s2 = ss[tid+off];
            float mm = fmaxf(m1, m2);
            ms[tid] = mm; ss[tid] = s1*expf(m1 - mm) + s2*expf(m2 - mm);
        }
        __syncthreads();
    }
    if (tid == 0){ pmax[blockIdx.x] = ms[0]; psum[blockIdx.x] = ss[0]; }
}

// ---------------- K10b: combine partials (B blocks, 1 wave) ----------------
__global__ void k_smcomb(const float* pmax, const float* psum,
                         float* maxv, float* sumv){
    int b = blockIdx.x, lane = threadIdx.x;  // 64 threads
    float m = (lane < NCH) ? pmax[b*NCH + lane] : -1e30f;
    float s = (lane < NCH) ? psum[b*NCH + lane] : 0.f;
    for (int off = 32; off > 0; off >>= 1){
        float m2 = __shfl_xor(m, off), s2 = __shfl_xor(s, off);
        float mm = fmaxf(m, m2);
        s = s*expf(m - mm) + s2*expf(m2 - mm);
        m = mm;
    }
    if (lane == 0){ maxv[b] = m; sumv[b] = s; }
}

// ---------------- K11: p_vocab (in place) + p_final base = pv*g ----------------
__global__ void k_final(const float* maxv, const float* sumv,
                        const float* pg, float* out){
    int t = blockIdx.x*256 + threadIdx.x;
    int b = blockIdx.y;
    if (t >= EXT) return;
    float g = pg[b];
    float pf;
    if (t < V){
        long idx = O_PVOCAB + (long)b*V + t;
        float lg = out[idx];
        float pv = expf(lg - maxv[b]) / sumv[b];
        out[idx] = pv;
        pf = pv*g;
    } else {
        pf = 0.f;
    }
    out[O_PFINAL + (long)b*EXT + t] = pf;
}

// ---------------- K11b: scatter-add (1-g)*att into p_final ----------------
__global__ void k_scatter(const int* fiv, const float* att, const float* pg,
                          float* out){
    int i = blockIdx.x*256 + threadIdx.x;   // B*S
    int b = i / S;
    float val = (1.f - pg[b]) * att[i];
    atomicAdd(&out[O_PFINAL + (long)b*EXT + fiv[i]], val);
}

// ---------------- K12: concat copies (float4) ----------------
__global__ void k_copies(const float* pdh, const float* pa, float* out){
    const long n1 = (long)B*T*H/4, n2 = (long)B*T*S/4;
    long i = (long)blockIdx.x*256 + threadIdx.x;
    long stride = (long)gridDim.x*256;
    for (; i < n1 + n2; i += stride){
        if (i < n1){
            long idx = i*4;
            int b = (int)(idx/(T*H)); int r = (int)(idx%(T*H)); int t = r/H; int k = r%H;
            *(f32x4*)(out + O_DECH + ((long)b*(T+1) + t)*H + k) = *(const f32x4*)(pdh + idx);
        } else {
            long idx = (i - n1)*4;
            int b = (int)(idx/(T*S)); int r = (int)(idx%(T*S)); int t = r/S; int s = r%S;
            *(f32x4*)(out + O_NPA + ((long)b*(T+1) + t)*S + s) = *(const f32x4*)(pa + idx);
        }
    }
}

extern "C" void kernel_launch(void* const* d_in, const int* in_sizes, int n_in,
                              void* d_out, int out_size, void* d_ws, size_t ws_size,
                              hipStream_t stream) {
    const int*   tok  = (const int*)d_in[0];
    const float* pdh  = (const float*)d_in[1];
    const float* lh   = (const float*)d_in[2];
    const float* enc  = (const float*)d_in[3];
    const int*   fiv  = (const int*)d_in[4];
    const float* pa   = (const float*)d_in[5];
    const float* emb  = (const float*)d_in[7];
    const float* Wih  = (const float*)d_in[8];
    const float* Whh  = (const float*)d_in[9];
    const float* bih  = (const float*)d_in[10];
    const float* bhh  = (const float*)d_in[11];
    const float* wh   = (const float*)d_in[12];
    const float* wd   = (const float*)d_in[13];
    const float* Woh  = (const float*)d_in[14];
    const float* boh  = (const float*)d_in[15];
    const float* Wov  = (const float*)d_in[16];
    const float* bov  = (const float*)d_in[17];
    const float* Wgen = (const float*)d_in[18];
    const float* bgen = (const float*)d_in[19];

    float* ws  = (float*)d_ws;
    float* out = (float*)d_out;

    float* x      = ws + OFF_X;
    float* g      = ws + OFF_G;
    float* Gg     = ws + OFF_GG;
    float* h      = ws + OFF_H;
    float* hw     = ws + OFF_HW;
    float* hwd    = ws + OFF_HWD;
    float* attd   = ws + OFF_ATTD;
    float* den    = ws + OFF_DEN;
    float* encp   = ws + OFF_ENCP;
    float* dec    = ws + OFF_DEC;
    float* att    = ws + OFF_ATT;
    float* pg     = ws + OFF_PG;
    float* maxv   = ws + OFF_MAX;
    float* sumv   = ws + OFF_SUM;
    short* projbf = (short*)(ws + OFF_PROJBF);
    float* pmax   = ws + OFF_PMAX;
    float* psum   = ws + OFF_PSUM;
    float* sc     = ws + OFF_SC;
    float* comb   = ws + OFF_COMB;   // overlays g (dead after k_gru)

    k_embed  <<<(B*E)/256, 256, 0, stream>>>(tok, emb, x);
    k_gates  <<<B*384, 256, 0, stream>>>(x, lh, Wih, Whh, bih, bhh, g, Gg);
    k_gru    <<<(B*H)/256, 256, 0, stream>>>(g, Gg, lh, wh, wd, h, hw, hwd, out);
    k_attdist<<<B*(S/4), 256, 0, stream>>>(hw, enc, attd, out);
    k_denom  <<<(B*S)/256, 256, 0, stream>>>(pa, den);
    k_attnorm<<<B, 256, 0, stream>>>(attd, den, att, out);
    k_encctx <<<B*4, 512, 0, stream>>>(att, enc, encp);
    k_decsc  <<<B, 256, 0, stream>>>(hwd, pdh, sc);
    k_decctx <<<B*4, 128, 0, stream>>>(sc, pdh, dec);
    k_comb   <<<B*6, 256, 0, stream>>>(h, encp, dec, comb);
    k_projgemm<<<B*(E/16), 256, 0, stream>>>(comb, Woh, boh, projbf);
    k_pgen   <<<B, 256, 0, stream>>>(comb, Wgen, bgen, pg, out);
    k_logits <<<V/16, 256, 0, stream>>>(projbf, Wov, bov, out);
    k_smpart <<<B*NCH, 256, 0, stream>>>(out + O_PVOCAB, pmax, psum);
    k_smcomb <<<B, 64, 0, stream>>>(pmax, psum, maxv, sumv);
    {
        dim3 grid((EXT + 255)/256, B);
        k_final<<<grid, 256, 0, stream>>>(maxv, sumv, pg, out);
    }
    k_scatter<<<(B*S)/256, 256, 0, stream>>>(fiv, att, pg, out);
    k_copies <<<2850, 256, 0, stream>>>(pdh, pa, out);
}

// Round 7
// 132.588 us; speedup vs baseline: 1.8738x; 1.1233x over previous
//
#include <hip/hip_runtime.h>
#include <hip/hip_bf16.h>

#define B 64
#define T 50
#define S 400
#define H 512
#define E 256
#define V 50000
#define EXT 50250
#define G3 1536
#define NCH 32
#define NCE 8

typedef __attribute__((ext_vector_type(8))) short short8;
typedef __attribute__((ext_vector_type(4))) float f32x4;

// ---- output offsets (f32 elements, return order) ----
#define O_PFINAL 0L
#define O_PGEN   3216000L
#define O_PVOCAB 3216064L
#define O_ATT    6416064L
#define O_DECH   6441664L
#define O_H      8112832L
#define O_NPA    8145600L

// ---- workspace offsets (f32 elements); total ~700K f32 = 2.8 MB (ws = 256 MB) ----
#define OFF_X      0L        /* B*E   */
#define OFF_G      16384L    /* B*G3 ; DEAD after k_gru -> comb overlays */
#define OFF_GG     114688L   /* B*G3  */
#define OFF_H      212992L   /* B*H   */
#define OFF_HW     245760L   /* B*H   */
#define OFF_HWD    278528L   /* B*H   */
#define OFF_ATTD   311296L   /* B*S   */
#define OFF_DEN    336896L   /* B*S   */
#define OFF_ENCP   362496L   /* B*NCE*H = 262144 */
#define OFF_DEC    624640L   /* B*H   */
#define OFF_ATT    657408L   /* B*S   */
#define OFF_PG     683008L   /* 64 */
#define OFF_MAX    683072L   /* 64 */
#define OFF_SUM    683136L   /* 64 */
#define OFF_PROJBF 683200L   /* 16384 bf16 = 8192 f32 slots */
#define OFF_PMAX   691392L   /* B*NCH */
#define OFF_PSUM   693440L   /* B*NCH */
#define OFF_SC     695488L   /* B*T -> end 698688 */
#define OFF_COMB   OFF_G     /* B*G3 overlay */

__device__ __forceinline__ float sigmoidf_(float x){ return 1.0f/(1.0f+expf(-x)); }
__device__ __forceinline__ short f2bs(float x){
    union { __hip_bfloat16 b; short s; } c; c.b = __float2bfloat16(x); return c.s;
}

// ---------------- K1a: embedding gather ----------------
__global__ void k_embed(const int* tok, const float* emb, float* x){
    int i = blockIdx.x*256 + threadIdx.x;   // B*E
    int b = i >> 8, e = i & 255;
    x[i] = emb[(long)tok[b]*E + e];
}

// ---------------- K1b: GRU gate pre-activations ----------------
__global__ void k_gates(const float* x, const float* lh,
                        const float* Wih, const float* Whh,
                        const float* bih, const float* bhh,
                        float* g, float* Gg){
    int blk = blockIdx.x;
    int b = blk / 384, jg = blk % 384;
    int wave = threadIdx.x >> 6, lane = threadIdx.x & 63;
    int j = jg*4 + wave;
    const float* xb = x + b*E;
    float gi = 0.f, gh = 0.f;
    #pragma unroll
    for (int m = 0; m < 4; m++)
        gi += xb[lane + 64*m] * Wih[(long)j*E + lane + 64*m];
    #pragma unroll
    for (int m = 0; m < 8; m++)
        gh += lh[b*H + lane + 64*m] * Whh[(long)j*H + lane + 64*m];
    for (int off = 32; off > 0; off >>= 1){
        gi += __shfl_xor(gi, off);
        gh += __shfl_xor(gh, off);
    }
    if (lane == 0){
        g [b*G3 + j] = gi + bih[j];
        Gg[b*G3 + j] = gh + bhh[j];
    }
}

// ---------------- K1c: GRU combine -> h, hw, hwd ----------------
__global__ void k_gru(const float* g, const float* Gg, const float* lh,
                      const float* wh, const float* wd,
                      float* h, float* hw, float* hwd, float* out){
    int i = blockIdx.x*256 + threadIdx.x;   // B*H
    int b = i >> 9, k = i & 511;
    float ir = g [b*G3 + k], iz = g [b*G3 + H + k], inn = g [b*G3 + 2*H + k];
    float hr = Gg[b*G3 + k], hz = Gg[b*G3 + H + k], hn  = Gg[b*G3 + 2*H + k];
    float r = sigmoidf_(ir + hr), z = sigmoidf_(iz + hz);
    float n = tanhf(inn + r*hn);
    float hp = lh[i];
    float hv = (1.f - z)*n + z*hp;
    h[i] = hv; hw[i] = hv * wh[k]; hwd[i] = hv * wd[k];
    out[O_H + i] = hv;
    out[O_DECH + ((long)b*(T+1) + T)*H + k] = hv;
}

// ---------------- K2: att_dist = h . (w_h * enc) ----------------
__global__ void k_attdist(const float* hw, const float* enc,
                          float* attd, float* out){
    int b = blockIdx.x / (S/4);
    int s = (blockIdx.x % (S/4))*4 + (threadIdx.x >> 6);
    int lane = threadIdx.x & 63;
    const float* ep = enc + ((long)b*S + s)*H + lane*8;
    f32x4 e0 = *(const f32x4*)(ep);
    f32x4 e1 = *(const f32x4*)(ep + 4);
    const float* hwp = hw + b*H + lane*8;
    f32x4 h0 = *(const f32x4*)(hwp);
    f32x4 h1 = *(const f32x4*)(hwp + 4);
    float acc = 0.f;
    #pragma unroll
    for (int m = 0; m < 4; m++) acc += h0[m]*e0[m] + h1[m]*e1[m];
    for (int off = 32; off > 0; off >>= 1) acc += __shfl_xor(acc, off);
    if (lane == 0){
        attd[b*S + s] = acc;
        out[O_NPA + ((long)b*(T+1) + T)*S + s] = acc;
    }
}

// ---------------- K3: temporal denominator ----------------
__global__ void k_denom(const float* pa, float* den){
    int i = blockIdx.x*256 + threadIdx.x;   // B*S
    int b = i / S, s = i % S;
    float sum = 0.f;
    for (int t = 0; t < T; t++)
        sum += expf(pa[((long)b*T + t)*S + s]);
    den[i] = sum;
}

// ---------------- K4: att normalize ----------------
__global__ void k_attnorm(const float* attd, const float* den,
                          float* att, float* out){
    int b = blockIdx.x, tid = threadIdx.x;
    __shared__ float tmp[S];
    __shared__ float red[256];
    float part = 0.f;
    for (int s = tid; s < S; s += 256){
        float e = expf(attd[b*S + s]) / den[b*S + s];
        tmp[s] = e; part += e;
    }
    red[tid] = part; __syncthreads();
    for (int off = 128; off > 0; off >>= 1){
        if (tid < off) red[tid] += red[tid + off];
        __syncthreads();
    }
    float inv = 1.f / red[0];
    for (int s = tid; s < S; s += 256){
        float a = tmp[s] * inv;
        att[b*S + s] = a;
        out[O_ATT + b*S + s] = a;
    }
}

// ---------------- K5: enc_ctx partials (NCE s-chunks) ----------------
__global__ void k_encctx(const float* att, const float* enc, float* encp){
    int b = blockIdx.x >> 3, c = blockIdx.x & 7;
    int k = threadIdx.x;  // 512 threads
    float acc = 0.f;
    for (int i = 0; i < S/NCE; i++){
        int s = c*(S/NCE) + i;
        acc += att[b*S + s] * enc[((long)b*S + s)*H + k];
    }
    encp[(b*NCE + c)*H + k] = acc;
}

// ---------------- K6a: decoder scores + softmax -> sc ----------------
__global__ void k_decsc(const float* hwd, const float* pdh, float* sc){
    int b = blockIdx.x;
    int wave = threadIdx.x >> 6, lane = threadIdx.x & 63;
    __shared__ float scs[T];
    for (int t = wave; t < T; t += 4){
        const float* pp = pdh + ((long)b*T + t)*H + lane*8;
        f32x4 p0 = *(const f32x4*)(pp);
        f32x4 p1 = *(const f32x4*)(pp + 4);
        const float* hp = hwd + b*H + lane*8;
        f32x4 h0 = *(const f32x4*)(hp);
        f32x4 h1 = *(const f32x4*)(hp + 4);
        float acc = 0.f;
        #pragma unroll
        for (int m = 0; m < 4; m++) acc += h0[m]*p0[m] + h1[m]*p1[m];
        for (int off = 32; off > 0; off >>= 1) acc += __shfl_xor(acc, off);
        if (lane == 0) scs[t] = acc;
    }
    __syncthreads();
    if (wave == 0){
        float xv = (lane < T) ? scs[lane] : -1e30f;
        float m = xv;
        for (int off = 32; off > 0; off >>= 1) m = fmaxf(m, __shfl_xor(m, off));
        float e = (lane < T) ? expf(xv - m) : 0.f;
        float ssum = e;
        for (int off = 32; off > 0; off >>= 1) ssum += __shfl_xor(ssum, off);
        if (lane < T) sc[b*T + lane] = e / ssum;
    }
}

// ---------------- K6b: decoder context (B*4 blocks, 128 thr) ----------------
__global__ void k_decctx(const float* sc, const float* pdh, float* dec){
    int b = blockIdx.x >> 2, c = blockIdx.x & 3;
    int k = c*128 + threadIdx.x;
    float acc = 0.f;
    for (int t = 0; t < T; t++)
        acc += sc[b*T + t] * pdh[((long)b*T + t)*H + k];
    dec[b*H + k] = acc;
}

// ---------------- K7a: build comb[B][G3] (grid = B*6, 256 thr) ----------------
__global__ void k_comb(const float* h, const float* encp, const float* dec,
                       float* comb){
    int blk = blockIdx.x;
    int b = blk / 6, j = (blk % 6)*256 + threadIdx.x;
    float v;
    if (j < H) v = h[b*H + j];
    else if (j < 2*H){
        int k = j - H;
        float s = 0.f;
        #pragma unroll
        for (int c = 0; c < NCE; c++) s += encp[(b*NCE + c)*H + k];
        v = s;
    } else v = dec[b*H + (j - 2*H)];
    comb[b*G3 + j] = v;
}

// ---------------- K7b: proj GEMM (grid = B*(E/16), 256 thr; wave -> 4 e) ----------------
__global__ void k_projgemm(const float* comb, const float* Woh, const float* boh,
                           short* projbf){
    int blk = blockIdx.x;
    int b = blk >> 4, et = blk & 15;
    int wave = threadIdx.x >> 6, lane = threadIdx.x & 63;
    int e0 = et*16 + wave*4;
    const float* cb = comb + b*G3;
    const float* w0 = Woh + (long)(e0+0)*G3;
    const float* w1 = Woh + (long)(e0+1)*G3;
    const float* w2 = Woh + (long)(e0+2)*G3;
    const float* w3 = Woh + (long)(e0+3)*G3;
    float a0=0.f, a1=0.f, a2=0.f, a3=0.f;
    #pragma unroll
    for (int m = 0; m < 24; m++){
        int idx = lane + 64*m;
        float c = cb[idx];
        a0 += c * w0[idx]; a1 += c * w1[idx];
        a2 += c * w2[idx]; a3 += c * w3[idx];
    }
    for (int off = 32; off > 0; off >>= 1){
        a0 += __shfl_xor(a0, off); a1 += __shfl_xor(a1, off);
        a2 += __shfl_xor(a2, off); a3 += __shfl_xor(a3, off);
    }
    if (lane == 0){
        projbf[b*E + e0+0] = f2bs(a0 + boh[e0+0]);
        projbf[b*E + e0+1] = f2bs(a1 + boh[e0+1]);
        projbf[b*E + e0+2] = f2bs(a2 + boh[e0+2]);
        projbf[b*E + e0+3] = f2bs(a3 + boh[e0+3]);
    }
}

// ---------------- K7c: p_gen (grid = B, 256 thr) ----------------
__global__ void k_pgen(const float* comb, const float* Wgen, const float* bgen,
                       float* pg, float* out){
    int b = blockIdx.x, tid = threadIdx.x;
    float part = 0.f;
    for (int j = tid; j < G3; j += 256)
        part += comb[b*G3 + j] * Wgen[j];
    __shared__ float red[256];
    red[tid] = part; __syncthreads();
    for (int off = 128; off > 0; off >>= 1){
        if (tid < off) red[tid] += red[tid + off];
        __syncthreads();
    }
    if (tid == 0){
        float pv = sigmoidf_(red[0] + bgen[0]);
        pg[b] = pv;
        out[O_PGEN + b] = pv;
    }
}

// ---------------- K9: logits (MFMA; 1 wave = 16 v-rows x ALL 64 batch) ----------------
// grid = V/16 = 3125 blocks, 64 thr. Wov read exactly once; 4 indep MFMA chains.
__global__ void __launch_bounds__(64) k_logits(const short* projbf, const float* Wov,
                         const float* bov, float* out){
    int lane = threadIdx.x;
    int vbase = blockIdx.x * 16;
    int row = lane & 15, kg = lane >> 4;
    f32x4 acc0 = {0.f,0.f,0.f,0.f}, acc1 = {0.f,0.f,0.f,0.f};
    f32x4 acc2 = {0.f,0.f,0.f,0.f}, acc3 = {0.f,0.f,0.f,0.f};
    const float* Bp = Wov + ((long)(vbase + row))*E + kg*8;
    const short* Ap = projbf + row*E + kg*8;
    #pragma unroll
    for (int ks = 0; ks < 8; ks++){
        f32x4 w0 = *(const f32x4*)(Bp + ks*32);
        f32x4 w1 = *(const f32x4*)(Bp + ks*32 + 4);
        short8 a0 = *(const short8*)(Ap + ks*32);
        short8 a1 = *(const short8*)(Ap + 16*E + ks*32);
        short8 a2 = *(const short8*)(Ap + 32*E + ks*32);
        short8 a3 = *(const short8*)(Ap + 48*E + ks*32);
        short8 bb;
        bb[0]=f2bs(w0[0]); bb[1]=f2bs(w0[1]); bb[2]=f2bs(w0[2]); bb[3]=f2bs(w0[3]);
        bb[4]=f2bs(w1[0]); bb[5]=f2bs(w1[1]); bb[6]=f2bs(w1[2]); bb[7]=f2bs(w1[3]);
        acc0 = __builtin_amdgcn_mfma_f32_16x16x32_bf16(a0, bb, acc0, 0, 0, 0);
        acc1 = __builtin_amdgcn_mfma_f32_16x16x32_bf16(a1, bb, acc1, 0, 0, 0);
        acc2 = __builtin_amdgcn_mfma_f32_16x16x32_bf16(a2, bb, acc2, 0, 0, 0);
        acc3 = __builtin_amdgcn_mfma_f32_16x16x32_bf16(a3, bb, acc3, 0, 0, 0);
    }
    int v = vbase + row;
    float bv = bov[v];
    #pragma unroll
    for (int r = 0; r < 4; r++){
        int bg = kg*4 + r;   // C/D: col=lane&15 (v), row=(lane>>4)*4+r (batch)
        out[O_PVOCAB + (long)(bg     )*V + v] = acc0[r] + bv;
        out[O_PVOCAB + (long)(bg + 16)*V + v] = acc1[r] + bv;
        out[O_PVOCAB + (long)(bg + 32)*V + v] = acc2[r] + bv;
        out[O_PVOCAB + (long)(bg + 48)*V + v] = acc3[r] + bv;
    }
}

// ---------------- K10a: partial online softmax (B*NCH blocks) ----------------
__global__ void k_smpart(const float* logits, float* pmax, float* psum){
    int b = blockIdx.x / NCH, c = blockIdx.x % NCH;
    const int chunk = (V + NCH - 1)/NCH;   // 1563
    int start = c*chunk;
    int end = start + chunk; if (end > V) end = V;
    float m = -1e30f, s = 0.f;
    for (int v = start + threadIdx.x; v < end; v += 256){
        float x = logits[(long)b*V + v];
        if (x > m){ s = s*expf(m - x) + 1.f; m = x; }
        else s += expf(x - m);
    }
    __shared__ float ms[256], ss[256];
    int tid = threadIdx.x;
    ms[tid] = m; ss[tid] = s; __syncthreads();
    for (int off = 128; off > 0; off >>= 1){
        if (tid < off){
            float m1 = ms[tid], m2 = ms[tid+off], s1 = ss[tid], s2 = ss[tid+off];
            float mm = fmaxf(m1, m2);
            ms[tid] = mm; ss[tid] = s1*expf(m1 - mm) + s2*expf(m2 - mm);
        }
        __syncthreads();
    }
    if (tid == 0){ pmax[blockIdx.x] = ms[0]; psum[blockIdx.x] = ss[0]; }
}

// ---------------- K10b: combine partials (B blocks, 1 wave) ----------------
__global__ void k_smcomb(const float* pmax, const float* psum,
                         float* maxv, float* sumv){
    int b = blockIdx.x, lane = threadIdx.x;  // 64 threads
    float m = (lane < NCH) ? pmax[b*NCH + lane] : -1e30f;
    float s = (lane < NCH) ? psum[b*NCH + lane] : 0.f;
    for (int off = 32; off > 0; off >>= 1){
        float m2 = __shfl_xor(m, off), s2 = __shfl_xor(s, off);
        float mm = fmaxf(m, m2);
        s = s*expf(m - mm) + s2*expf(m2 - mm);
        m = mm;
    }
    if (lane == 0){ maxv[b] = m; sumv[b] = s; }
}

// ---------------- K11: p_vocab (in place) + p_final base = pv*g ----------------
__global__ void k_final(const float* maxv, const float* sumv,
                        const float* pg, float* out){
    int t = blockIdx.x*256 + threadIdx.x;
    int b = blockIdx.y;
    if (t >= EXT) return;
    float g = pg[b];
    float pf;
    if (t < V){
        long idx = O_PVOCAB + (long)b*V + t;
        float lg = out[idx];
        float pv = expf(lg - maxv[b]) / sumv[b];
        out[idx] = pv;
        pf = pv*g;
    } else {
        pf = 0.f;
    }
    out[O_PFINAL + (long)b*EXT + t] = pf;
}

// ---------------- K11b: scatter-add (1-g)*att into p_final ----------------
__global__ void k_scatter(const int* fiv, const float* att, const float* pg,
                          float* out){
    int i = blockIdx.x*256 + threadIdx.x;   // B*S
    int b = i / S;
    float val = (1.f - pg[b]) * att[i];
    atomicAdd(&out[O_PFINAL + (long)b*EXT + fiv[i]], val);
}

// ---------------- K12: concat copies (float4) ----------------
__global__ void k_copies(const float* pdh, const float* pa, float* out){
    const long n1 = (long)B*T*H/4, n2 = (long)B*T*S/4;
    long i = (long)blockIdx.x*256 + threadIdx.x;
    long stride = (long)gridDim.x*256;
    for (; i < n1 + n2; i += stride){
        if (i < n1){
            long idx = i*4;
            int b = (int)(idx/(T*H)); int r = (int)(idx%(T*H)); int t = r/H; int k = r%H;
            *(f32x4*)(out + O_DECH + ((long)b*(T+1) + t)*H + k) = *(const f32x4*)(pdh + idx);
        } else {
            long idx = (i - n1)*4;
            int b = (int)(idx/(T*S)); int r = (int)(idx%(T*S)); int t = r/S; int s = r%S;
            *(f32x4*)(out + O_NPA + ((long)b*(T+1) + t)*S + s) = *(const f32x4*)(pa + idx);
        }
    }
}

extern "C" void kernel_launch(void* const* d_in, const int* in_sizes, int n_in,
                              void* d_out, int out_size, void* d_ws, size_t ws_size,
                              hipStream_t stream) {
    const int*   tok  = (const int*)d_in[0];
    const float* pdh  = (const float*)d_in[1];
    const float* lh   = (const float*)d_in[2];
    const float* enc  = (const float*)d_in[3];
    const int*   fiv  = (const int*)d_in[4];
    const float* pa   = (const float*)d_in[5];
    const float* emb  = (const float*)d_in[7];
    const float* Wih  = (const float*)d_in[8];
    const float* Whh  = (const float*)d_in[9];
    const float* bih  = (const float*)d_in[10];
    const float* bhh  = (const float*)d_in[11];
    const float* wh   = (const float*)d_in[12];
    const float* wd   = (const float*)d_in[13];
    const float* Woh  = (const float*)d_in[14];
    const float* boh  = (const float*)d_in[15];
    const float* Wov  = (const float*)d_in[16];
    const float* bov  = (const float*)d_in[17];
    const float* Wgen = (const float*)d_in[18];
    const float* bgen = (const float*)d_in[19];

    float* ws  = (float*)d_ws;
    float* out = (float*)d_out;

    float* x      = ws + OFF_X;
    float* g      = ws + OFF_G;
    float* Gg     = ws + OFF_GG;
    float* h      = ws + OFF_H;
    float* hw     = ws + OFF_HW;
    float* hwd    = ws + OFF_HWD;
    float* attd   = ws + OFF_ATTD;
    float* den    = ws + OFF_DEN;
    float* encp   = ws + OFF_ENCP;
    float* dec    = ws + OFF_DEC;
    float* att    = ws + OFF_ATT;
    float* pg     = ws + OFF_PG;
    float* maxv   = ws + OFF_MAX;
    float* sumv   = ws + OFF_SUM;
    short* projbf = (short*)(ws + OFF_PROJBF);
    float* pmax   = ws + OFF_PMAX;
    float* psum   = ws + OFF_PSUM;
    float* sc     = ws + OFF_SC;
    float* comb   = ws + OFF_COMB;   // overlays g (dead after k_gru)

    k_embed  <<<(B*E)/256, 256, 0, stream>>>(tok, emb, x);
    k_gates  <<<B*384, 256, 0, stream>>>(x, lh, Wih, Whh, bih, bhh, g, Gg);
    k_gru    <<<(B*H)/256, 256, 0, stream>>>(g, Gg, lh, wh, wd, h, hw, hwd, out);
    k_attdist<<<B*(S/4), 256, 0, stream>>>(hw, enc, attd, out);
    k_denom  <<<(B*S)/256, 256, 0, stream>>>(pa, den);
    k_attnorm<<<B, 256, 0, stream>>>(attd, den, att, out);
    k_encctx <<<B*NCE, 512, 0, stream>>>(att, enc, encp);
    k_decsc  <<<B, 256, 0, stream>>>(hwd, pdh, sc);
    k_decctx <<<B*4, 128, 0, stream>>>(sc, pdh, dec);
    k_comb   <<<B*6, 256, 0, stream>>>(h, encp, dec, comb);
    k_projgemm<<<B*(E/16), 256, 0, stream>>>(comb, Woh, boh, projbf);
    k_pgen   <<<B, 256, 0, stream>>>(comb, Wgen, bgen, pg, out);
    k_logits <<<V/16, 64, 0, stream>>>(projbf, Wov, bov, out);
    k_smpart <<<B*NCH, 256, 0, stream>>>(out + O_PVOCAB, pmax, psum);
    k_smcomb <<<B, 64, 0, stream>>>(pmax, psum, maxv, sumv);
    {
        dim3 grid((EXT + 255)/256, B);
        k_final<<<grid, 256, 0, stream>>>(maxv, sumv, pg, out);
    }
    k_scatter<<<(B*S)/256, 256, 0, stream>>>(fiv, att, pg, out);
    k_copies <<<2850, 256, 0, stream>>>(pdh, pa, out);
}

// Round 8
// 125.158 us; speedup vs baseline: 1.9850x; 1.0594x over previous
//
#include <hip/hip_runtime.h>
#include <hip/hip_bf16.h>

#define B 64
#define T 50
#define S 400
#define H 512
#define E 256
#define V 50000
#define EXT 50250
#define G3 1536
#define NCH 32
#define NCE 8

typedef __attribute__((ext_vector_type(8))) short short8;
typedef __attribute__((ext_vector_type(4))) float f32x4;

// ---- output offsets (f32 elements, return order) ----
#define O_PFINAL 0L
#define O_PGEN   3216000L
#define O_PVOCAB 3216064L
#define O_ATT    6416064L
#define O_DECH   6441664L
#define O_H      8112832L
#define O_NPA    8145600L

// ---- workspace offsets (f32 elements); ws = 256 MB, using ~2.9 MB ----
#define OFF_G      16384L    /* B*G3 ; DEAD after k_gru -> comb overlays */
#define OFF_GG     114688L   /* B*G3  */
#define OFF_H      212992L   /* B*H   */
#define OFF_HW     245760L   /* B*H   */
#define OFF_HWD    278528L   /* B*H   */
#define OFF_ATTD   311296L   /* B*S   */
#define OFF_ENCP   362496L   /* B*NCE*H = 262144 */
#define OFF_DEC    624640L   /* B*H   */
#define OFF_ATT    657408L   /* B*S   */
#define OFF_PG     683008L   /* 64 */
#define OFF_PROJBF 683200L   /* 16384 bf16 = 8192 f32 slots */
#define OFF_PMAX   691392L   /* B*NCH */
#define OFF_PSUM   693440L   /* B*NCH */
#define OFF_SC     695488L   /* B*T */
#define OFF_XH     698688L   /* B*768 bf16 = 24576 f32 slots -> end 723264 */
#define OFF_COMB   OFF_G     /* B*G3 overlay */

__device__ __forceinline__ float sigmoidf_(float x){ return 1.0f/(1.0f+expf(-x)); }
__device__ __forceinline__ short f2bs(float x){
    union { __hip_bfloat16 b; short s; } c; c.b = __float2bfloat16(x); return c.s;
}

// ---------------- K0: xh = [emb[tok] | lh] as bf16 ----------------
__global__ void k_xh(const int* tok, const float* emb, const float* lh, short* xh){
    int i = blockIdx.x*256 + threadIdx.x;   // B*768
    int b = i / 768, j = i % 768;
    float v = (j < E) ? emb[(long)tok[b]*E + j] : lh[b*H + (j - E)];
    xh[i] = f2bs(v);
}

// ---------------- K1: GRU gates via MFMA ----------------
// grid = G3/16 = 96 blocks, 128 thr. wave0: gi (K=256); wave1: gh (K=512).
// Weights read exactly once, converted f32->bf16 inline.
__global__ void __launch_bounds__(128) k_gates(const short* xh,
                        const float* Wih, const float* Whh,
                        const float* bih, const float* bhh,
                        float* g, float* Gg){
    int lane = threadIdx.x & 63, wave = threadIdx.x >> 6;
    int row = lane & 15, kg = lane >> 4;
    int j = blockIdx.x*16 + row;
    f32x4 c0={0.f,0.f,0.f,0.f}, c1={0.f,0.f,0.f,0.f};
    f32x4 c2={0.f,0.f,0.f,0.f}, c3={0.f,0.f,0.f,0.f};
    if (wave == 0){
        const float* Wp = Wih + (long)j*E + kg*8;
        const short* Ap = xh + row*768 + kg*8;
        #pragma unroll
        for (int ks = 0; ks < 8; ks++){
            f32x4 w0 = *(const f32x4*)(Wp + ks*32);
            f32x4 w1 = *(const f32x4*)(Wp + ks*32 + 4);
            short8 bb;
            bb[0]=f2bs(w0[0]); bb[1]=f2bs(w0[1]); bb[2]=f2bs(w0[2]); bb[3]=f2bs(w0[3]);
            bb[4]=f2bs(w1[0]); bb[5]=f2bs(w1[1]); bb[6]=f2bs(w1[2]); bb[7]=f2bs(w1[3]);
            short8 a0 = *(const short8*)(Ap + ks*32);
            short8 a1 = *(const short8*)(Ap + 16*768 + ks*32);
            short8 a2 = *(const short8*)(Ap + 32*768 + ks*32);
            short8 a3 = *(const short8*)(Ap + 48*768 + ks*32);
            c0 = __builtin_amdgcn_mfma_f32_16x16x32_bf16(a0, bb, c0, 0, 0, 0);
            c1 = __builtin_amdgcn_mfma_f32_16x16x32_bf16(a1, bb, c1, 0, 0, 0);
            c2 = __builtin_amdgcn_mfma_f32_16x16x32_bf16(a2, bb, c2, 0, 0, 0);
            c3 = __builtin_amdgcn_mfma_f32_16x16x32_bf16(a3, bb, c3, 0, 0, 0);
        }
        float bi = bih[j];
        #pragma unroll
        for (int r = 0; r < 4; r++){
            int bg = kg*4 + r;
            g[(long)(bg     )*G3 + j] = c0[r] + bi;
            g[(long)(bg + 16)*G3 + j] = c1[r] + bi;
            g[(long)(bg + 32)*G3 + j] = c2[r] + bi;
            g[(long)(bg + 48)*G3 + j] = c3[r] + bi;
        }
    } else {
        const float* Wp = Whh + (long)j*H + kg*8;
        const short* Ap = xh + row*768 + 256 + kg*8;
        #pragma unroll
        for (int ks = 0; ks < 16; ks++){
            f32x4 w0 = *(const f32x4*)(Wp + ks*32);
            f32x4 w1 = *(const f32x4*)(Wp + ks*32 + 4);
            short8 bb;
            bb[0]=f2bs(w0[0]); bb[1]=f2bs(w0[1]); bb[2]=f2bs(w0[2]); bb[3]=f2bs(w0[3]);
            bb[4]=f2bs(w1[0]); bb[5]=f2bs(w1[1]); bb[6]=f2bs(w1[2]); bb[7]=f2bs(w1[3]);
            short8 a0 = *(const short8*)(Ap + ks*32);
            short8 a1 = *(const short8*)(Ap + 16*768 + ks*32);
            short8 a2 = *(const short8*)(Ap + 32*768 + ks*32);
            short8 a3 = *(const short8*)(Ap + 48*768 + ks*32);
            c0 = __builtin_amdgcn_mfma_f32_16x16x32_bf16(a0, bb, c0, 0, 0, 0);
            c1 = __builtin_amdgcn_mfma_f32_16x16x32_bf16(a1, bb, c1, 0, 0, 0);
            c2 = __builtin_amdgcn_mfma_f32_16x16x32_bf16(a2, bb, c2, 0, 0, 0);
            c3 = __builtin_amdgcn_mfma_f32_16x16x32_bf16(a3, bb, c3, 0, 0, 0);
        }
        float bh = bhh[j];
        #pragma unroll
        for (int r = 0; r < 4; r++){
            int bg = kg*4 + r;
            Gg[(long)(bg     )*G3 + j] = c0[r] + bh;
            Gg[(long)(bg + 16)*G3 + j] = c1[r] + bh;
            Gg[(long)(bg + 32)*G3 + j] = c2[r] + bh;
            Gg[(long)(bg + 48)*G3 + j] = c3[r] + bh;
        }
    }
}

// ---------------- K1c: GRU combine -> h, hw, hwd ----------------
__global__ void k_gru(const float* g, const float* Gg, const float* lh,
                      const float* wh, const float* wd,
                      float* h, float* hw, float* hwd, float* out){
    int i = blockIdx.x*256 + threadIdx.x;   // B*H
    int b = i >> 9, k = i & 511;
    float ir = g [b*G3 + k], iz = g [b*G3 + H + k], inn = g [b*G3 + 2*H + k];
    float hr = Gg[b*G3 + k], hz = Gg[b*G3 + H + k], hn  = Gg[b*G3 + 2*H + k];
    float r = sigmoidf_(ir + hr), z = sigmoidf_(iz + hz);
    float n = tanhf(inn + r*hn);
    float hp = lh[i];
    float hv = (1.f - z)*n + z*hp;
    h[i] = hv; hw[i] = hv * wh[k]; hwd[i] = hv * wd[k];
    out[O_H + i] = hv;
    out[O_DECH + ((long)b*(T+1) + T)*H + k] = hv;
}

// ---------------- K2: att_dist = h . (w_h * enc) ----------------
__global__ void k_attdist(const float* hw, const float* enc,
                          float* attd, float* out){
    int b = blockIdx.x / (S/4);
    int s = (blockIdx.x % (S/4))*4 + (threadIdx.x >> 6);
    int lane = threadIdx.x & 63;
    const float* ep = enc + ((long)b*S + s)*H + lane*8;
    f32x4 e0 = *(const f32x4*)(ep);
    f32x4 e1 = *(const f32x4*)(ep + 4);
    const float* hwp = hw + b*H + lane*8;
    f32x4 h0 = *(const f32x4*)(hwp);
    f32x4 h1 = *(const f32x4*)(hwp + 4);
    float acc = 0.f;
    #pragma unroll
    for (int m = 0; m < 4; m++) acc += h0[m]*e0[m] + h1[m]*e1[m];
    for (int off = 32; off > 0; off >>= 1) acc += __shfl_xor(acc, off);
    if (lane == 0){
        attd[b*S + s] = acc;
        out[O_NPA + ((long)b*(T+1) + T)*S + s] = acc;
    }
}

// ---------------- K4: att normalize (temporal denom fused) ----------------
__global__ void k_attnorm(const float* attd, const float* pa,
                          float* att, float* out){
    int b = blockIdx.x, tid = threadIdx.x;
    __shared__ float tmp[S];
    __shared__ float red[256];
    float part = 0.f;
    for (int s = tid; s < S; s += 256){
        float d = 0.f;
        for (int t = 0; t < T; t++)
            d += expf(pa[((long)b*T + t)*S + s]);
        float e = expf(attd[b*S + s]) / d;
        tmp[s] = e; part += e;
    }
    red[tid] = part; __syncthreads();
    for (int off = 128; off > 0; off >>= 1){
        if (tid < off) red[tid] += red[tid + off];
        __syncthreads();
    }
    float inv = 1.f / red[0];
    for (int s = tid; s < S; s += 256){
        float a = tmp[s] * inv;
        att[b*S + s] = a;
        out[O_ATT + b*S + s] = a;
    }
}

// ---------------- K5: enc_ctx partials (NCE s-chunks) ----------------
__global__ void k_encctx(const float* att, const float* enc, float* encp){
    int b = blockIdx.x >> 3, c = blockIdx.x & 7;
    int k = threadIdx.x;  // 512 threads
    float acc = 0.f;
    for (int i = 0; i < S/NCE; i++){
        int s = c*(S/NCE) + i;
        acc += att[b*S + s] * enc[((long)b*S + s)*H + k];
    }
    encp[(b*NCE + c)*H + k] = acc;
}

// ---------------- K6a: decoder scores + softmax -> sc ----------------
__global__ void k_decsc(const float* hwd, const float* pdh, float* sc){
    int b = blockIdx.x;
    int wave = threadIdx.x >> 6, lane = threadIdx.x & 63;
    __shared__ float scs[T];
    for (int t = wave; t < T; t += 4){
        const float* pp = pdh + ((long)b*T + t)*H + lane*8;
        f32x4 p0 = *(const f32x4*)(pp);
        f32x4 p1 = *(const f32x4*)(pp + 4);
        const float* hp = hwd + b*H + lane*8;
        f32x4 h0 = *(const f32x4*)(hp);
        f32x4 h1 = *(const f32x4*)(hp + 4);
        float acc = 0.f;
        #pragma unroll
        for (int m = 0; m < 4; m++) acc += h0[m]*p0[m] + h1[m]*p1[m];
        for (int off = 32; off > 0; off >>= 1) acc += __shfl_xor(acc, off);
        if (lane == 0) scs[t] = acc;
    }
    __syncthreads();
    if (wave == 0){
        float xv = (lane < T) ? scs[lane] : -1e30f;
        float m = xv;
        for (int off = 32; off > 0; off >>= 1) m = fmaxf(m, __shfl_xor(m, off));
        float e = (lane < T) ? expf(xv - m) : 0.f;
        float ssum = e;
        for (int off = 32; off > 0; off >>= 1) ssum += __shfl_xor(ssum, off);
        if (lane < T) sc[b*T + lane] = e / ssum;
    }
}

// ---------------- K6b: decoder context (B*4 blocks, 128 thr) ----------------
__global__ void k_decctx(const float* sc, const float* pdh, float* dec){
    int b = blockIdx.x >> 2, c = blockIdx.x & 3;
    int k = c*128 + threadIdx.x;
    float acc = 0.f;
    for (int t = 0; t < T; t++)
        acc += sc[b*T + t] * pdh[((long)b*T + t)*H + k];
    dec[b*H + k] = acc;
}

// ---------------- K7a: comb build + p_gen (grid = B, 512 thr) ----------------
__global__ void k_combgen(const float* h, const float* encp, const float* dec,
                          const float* Wgen, const float* bgen,
                          float* comb, float* pg, float* out){
    int b = blockIdx.x, tid = threadIdx.x;  // 512
    float v0 = h[b*H + tid];
    float v1 = 0.f;
    #pragma unroll
    for (int c = 0; c < NCE; c++) v1 += encp[(b*NCE + c)*H + tid];
    float v2 = dec[b*H + tid];
    comb[b*G3 + tid]       = v0;
    comb[b*G3 + H + tid]   = v1;
    comb[b*G3 + 2*H + tid] = v2;
    float part = v0*Wgen[tid] + v1*Wgen[H + tid] + v2*Wgen[2*H + tid];
    __shared__ float red[512];
    red[tid] = part; __syncthreads();
    for (int off = 256; off > 0; off >>= 1){
        if (tid < off) red[tid] += red[tid + off];
        __syncthreads();
    }
    if (tid == 0){
        float pv = sigmoidf_(red[0] + bgen[0]);
        pg[b] = pv;
        out[O_PGEN + b] = pv;
    }
}

// ---------------- K7b: proj GEMM (grid = B*(E/16), 256 thr; wave -> 4 e) ----------------
__global__ void k_projgemm(const float* comb, const float* Woh, const float* boh,
                           short* projbf){
    int blk = blockIdx.x;
    int b = blk >> 4, et = blk & 15;
    int wave = threadIdx.x >> 6, lane = threadIdx.x & 63;
    int e0 = et*16 + wave*4;
    const float* cb = comb + b*G3;
    const float* w0 = Woh + (long)(e0+0)*G3;
    const float* w1 = Woh + (long)(e0+1)*G3;
    const float* w2 = Woh + (long)(e0+2)*G3;
    const float* w3 = Woh + (long)(e0+3)*G3;
    float a0=0.f, a1=0.f, a2=0.f, a3=0.f;
    #pragma unroll
    for (int m = 0; m < 24; m++){
        int idx = lane + 64*m;
        float c = cb[idx];
        a0 += c * w0[idx]; a1 += c * w1[idx];
        a2 += c * w2[idx]; a3 += c * w3[idx];
    }
    for (int off = 32; off > 0; off >>= 1){
        a0 += __shfl_xor(a0, off); a1 += __shfl_xor(a1, off);
        a2 += __shfl_xor(a2, off); a3 += __shfl_xor(a3, off);
    }
    if (lane == 0){
        projbf[b*E + e0+0] = f2bs(a0 + boh[e0+0]);
        projbf[b*E + e0+1] = f2bs(a1 + boh[e0+1]);
        projbf[b*E + e0+2] = f2bs(a2 + boh[e0+2]);
        projbf[b*E + e0+3] = f2bs(a3 + boh[e0+3]);
    }
}

// ---------------- K9: logits (MFMA; 1 wave = 16 v-rows x ALL 64 batch) ----------------
__global__ void __launch_bounds__(64) k_logits(const short* projbf, const float* Wov,
                         const float* bov, float* out){
    int lane = threadIdx.x;
    int vbase = blockIdx.x * 16;
    int row = lane & 15, kg = lane >> 4;
    f32x4 acc0 = {0.f,0.f,0.f,0.f}, acc1 = {0.f,0.f,0.f,0.f};
    f32x4 acc2 = {0.f,0.f,0.f,0.f}, acc3 = {0.f,0.f,0.f,0.f};
    const float* Bp = Wov + ((long)(vbase + row))*E + kg*8;
    const short* Ap = projbf + row*E + kg*8;
    #pragma unroll
    for (int ks = 0; ks < 8; ks++){
        f32x4 w0 = *(const f32x4*)(Bp + ks*32);
        f32x4 w1 = *(const f32x4*)(Bp + ks*32 + 4);
        short8 a0 = *(const short8*)(Ap + ks*32);
        short8 a1 = *(const short8*)(Ap + 16*E + ks*32);
        short8 a2 = *(const short8*)(Ap + 32*E + ks*32);
        short8 a3 = *(const short8*)(Ap + 48*E + ks*32);
        short8 bb;
        bb[0]=f2bs(w0[0]); bb[1]=f2bs(w0[1]); bb[2]=f2bs(w0[2]); bb[3]=f2bs(w0[3]);
        bb[4]=f2bs(w1[0]); bb[5]=f2bs(w1[1]); bb[6]=f2bs(w1[2]); bb[7]=f2bs(w1[3]);
        acc0 = __builtin_amdgcn_mfma_f32_16x16x32_bf16(a0, bb, acc0, 0, 0, 0);
        acc1 = __builtin_amdgcn_mfma_f32_16x16x32_bf16(a1, bb, acc1, 0, 0, 0);
        acc2 = __builtin_amdgcn_mfma_f32_16x16x32_bf16(a2, bb, acc2, 0, 0, 0);
        acc3 = __builtin_amdgcn_mfma_f32_16x16x32_bf16(a3, bb, acc3, 0, 0, 0);
    }
    int v = vbase + row;
    float bv = bov[v];
    #pragma unroll
    for (int r = 0; r < 4; r++){
        int bg = kg*4 + r;
        out[O_PVOCAB + (long)(bg     )*V + v] = acc0[r] + bv;
        out[O_PVOCAB + (long)(bg + 16)*V + v] = acc1[r] + bv;
        out[O_PVOCAB + (long)(bg + 32)*V + v] = acc2[r] + bv;
        out[O_PVOCAB + (long)(bg + 48)*V + v] = acc3[r] + bv;
    }
}

// ---------------- K10a: partial online softmax (B*NCH blocks) ----------------
__global__ void k_smpart(const float* logits, float* pmax, float* psum){
    int b = blockIdx.x / NCH, c = blockIdx.x % NCH;
    const int chunk = (V + NCH - 1)/NCH;   // 1563
    int start = c*chunk;
    int end = start + chunk; if (end > V) end = V;
    float m = -1e30f, s = 0.f;
    for (int v = start + threadIdx.x; v < end; v += 256){
        float x = logits[(long)b*V + v];
        if (x > m){ s = s*expf(m - x) + 1.f; m = x; }
        else s += expf(x - m);
    }
    __shared__ float ms[256], ss[256];
    int tid = threadIdx.x;
    ms[tid] = m; ss[tid] = s; __syncthreads();
    for (int off = 128; off > 0; off >>= 1){
        if (tid < off){
            float m1 = ms[tid], m2 = ms[tid+off], s1 = ss[tid], s2 = ss[tid+off];
            float mm = fmaxf(m1, m2);
            ms[tid] = mm; ss[tid] = s1*expf(m1 - mm) + s2*expf(m2 - mm);
        }
        __syncthreads();
    }
    if (tid == 0){ pmax[blockIdx.x] = ms[0]; psum[blockIdx.x] = ss[0]; }
}

// ---------------- K11: p_vocab + p_final base (smcomb inlined) ----------------
__global__ void k_final(const float* pmax, const float* psum,
                        const float* pg, float* out){
    __shared__ float sm[2];
    int b = blockIdx.y;
    if (threadIdx.x < 64){
        int lane = threadIdx.x;
        float m = (lane < NCH) ? pmax[b*NCH + lane] : -1e30f;
        float s = (lane < NCH) ? psum[b*NCH + lane] : 0.f;
        for (int off = 32; off > 0; off >>= 1){
            float m2 = __shfl_xor(m, off), s2 = __shfl_xor(s, off);
            float mm = fmaxf(m, m2);
            s = s*expf(m - mm) + s2*expf(m2 - mm);
            m = mm;
        }
        if (lane == 0){ sm[0] = m; sm[1] = s; }
    }
    __syncthreads();
    float mv = sm[0], inv = 1.f / sm[1];
    int t = blockIdx.x*256 + threadIdx.x;
    if (t >= EXT) return;
    float g = pg[b];
    float pf;
    if (t < V){
        long idx = O_PVOCAB + (long)b*V + t;
        float pv = expf(out[idx] - mv) * inv;
        out[idx] = pv;
        pf = pv*g;
    } else {
        pf = 0.f;
    }
    out[O_PFINAL + (long)b*EXT + t] = pf;
}

// ---------------- K11b: scatter-add (1-g)*att into p_final ----------------
__global__ void k_scatter(const int* fiv, const float* att, const float* pg,
                          float* out){
    int i = blockIdx.x*256 + threadIdx.x;   // B*S
    int b = i / S;
    float val = (1.f - pg[b]) * att[i];
    atomicAdd(&out[O_PFINAL + (long)b*EXT + fiv[i]], val);
}

// ---------------- K12: concat copies (float4) ----------------
__global__ void k_copies(const float* pdh, const float* pa, float* out){
    const long n1 = (long)B*T*H/4, n2 = (long)B*T*S/4;
    long i = (long)blockIdx.x*256 + threadIdx.x;
    long stride = (long)gridDim.x*256;
    for (; i < n1 + n2; i += stride){
        if (i < n1){
            long idx = i*4;
            int b = (int)(idx/(T*H)); int r = (int)(idx%(T*H)); int t = r/H; int k = r%H;
            *(f32x4*)(out + O_DECH + ((long)b*(T+1) + t)*H + k) = *(const f32x4*)(pdh + idx);
        } else {
            long idx = (i - n1)*4;
            int b = (int)(idx/(T*S)); int r = (int)(idx%(T*S)); int t = r/S; int s = r%S;
            *(f32x4*)(out + O_NPA + ((long)b*(T+1) + t)*S + s) = *(const f32x4*)(pa + idx);
        }
    }
}

extern "C" void kernel_launch(void* const* d_in, const int* in_sizes, int n_in,
                              void* d_out, int out_size, void* d_ws, size_t ws_size,
                              hipStream_t stream) {
    const int*   tok  = (const int*)d_in[0];
    const float* pdh  = (const float*)d_in[1];
    const float* lh   = (const float*)d_in[2];
    const float* enc  = (const float*)d_in[3];
    const int*   fiv  = (const int*)d_in[4];
    const float* pa   = (const float*)d_in[5];
    const float* emb  = (const float*)d_in[7];
    const float* Wih  = (const float*)d_in[8];
    const float* Whh  = (const float*)d_in[9];
    const float* bih  = (const float*)d_in[10];
    const float* bhh  = (const float*)d_in[11];
    const float* wh   = (const float*)d_in[12];
    const float* wd   = (const float*)d_in[13];
    const float* Woh  = (const float*)d_in[14];
    const float* boh  = (const float*)d_in[15];
    const float* Wov  = (const float*)d_in[16];
    const float* bov  = (const float*)d_in[17];
    const float* Wgen = (const float*)d_in[18];
    const float* bgen = (const float*)d_in[19];

    float* ws  = (float*)d_ws;
    float* out = (float*)d_out;

    float* g      = ws + OFF_G;
    float* Gg     = ws + OFF_GG;
    float* h      = ws + OFF_H;
    float* hw     = ws + OFF_HW;
    float* hwd    = ws + OFF_HWD;
    float* attd   = ws + OFF_ATTD;
    float* encp   = ws + OFF_ENCP;
    float* dec    = ws + OFF_DEC;
    float* att    = ws + OFF_ATT;
    float* pg     = ws + OFF_PG;
    short* projbf = (short*)(ws + OFF_PROJBF);
    float* pmax   = ws + OFF_PMAX;
    float* psum   = ws + OFF_PSUM;
    float* sc     = ws + OFF_SC;
    short* xh     = (short*)(ws + OFF_XH);
    float* comb   = ws + OFF_COMB;   // overlays g (dead after k_gru)

    k_xh     <<<(B*768)/256, 256, 0, stream>>>(tok, emb, lh, xh);
    k_gates  <<<G3/16, 128, 0, stream>>>(xh, Wih, Whh, bih, bhh, g, Gg);
    k_gru    <<<(B*H)/256, 256, 0, stream>>>(g, Gg, lh, wh, wd, h, hw, hwd, out);
    k_attdist<<<B*(S/4), 256, 0, stream>>>(hw, enc, attd, out);
    k_attnorm<<<B, 256, 0, stream>>>(attd, pa, att, out);
    k_encctx <<<B*NCE, 512, 0, stream>>>(att, enc, encp);
    k_decsc  <<<B, 256, 0, stream>>>(hwd, pdh, sc);
    k_decctx <<<B*4, 128, 0, stream>>>(sc, pdh, dec);
    k_combgen<<<B, 512, 0, stream>>>(h, encp, dec, Wgen, bgen, comb, pg, out);
    k_projgemm<<<B*(E/16), 256, 0, stream>>>(comb, Woh, boh, projbf);
    k_logits <<<V/16, 64, 0, stream>>>(projbf, Wov, bov, out);
    k_smpart <<<B*NCH, 256, 0, stream>>>(out + O_PVOCAB, pmax, psum);
    {
        dim3 grid((EXT + 255)/256, B);
        k_final<<<grid, 256, 0, stream>>>(pmax, psum, pg, out);
    }
    k_scatter<<<(B*S)/256, 256, 0, stream>>>(fiv, att, pg, out);
    k_copies <<<2850, 256, 0, stream>>>(pdh, pa, out);
}

// Round 9
// 99.122 us; speedup vs baseline: 2.5065x; 1.2627x over previous
//
#include <hip/hip_runtime.h>
#include <hip/hip_bf16.h>

#define B 64
#define T 50
#define S 400
#define H 512
#define E 256
#define V 50000
#define EXT 50250
#define G3 1536
#define NCH 32
#define NCE 8

typedef __attribute__((ext_vector_type(8))) short short8;
typedef __attribute__((ext_vector_type(4))) float f32x4;

// ---- output offsets (f32 elements, return order) ----
#define O_PFINAL 0L
#define O_PGEN   3216000L
#define O_PVOCAB 3216064L
#define O_ATT    6416064L
#define O_DECH   6441664L
#define O_H      8112832L
#define O_NPA    8145600L

// ---- workspace offsets (f32 elements); ws = 256 MB ----
#define OFF_G      0L        /* B*G3 */
#define OFF_GG     98304L    /* B*G3 */
#define OFF_H      196608L   /* B*H  */
#define OFF_HW     229376L   /* B*H  */
#define OFF_HWD    262144L   /* B*H  */
#define OFF_ATTD   294912L   /* B*S  */
#define OFF_ENCP   320512L   /* B*NCE*H */
#define OFF_DEC    582656L   /* B*H  */
#define OFF_ATT    615424L   /* B*S  */
#define OFF_PG     641024L   /* 64 */
#define OFF_PROJBF 641152L   /* 16384 bf16 = 8192 f32 */
#define OFF_PSUM   649344L   /* B*NCH */
#define OFF_SC     651392L   /* B*T */
#define OFF_TOK    1048576L  /* B*EXT f32 = 12.9 MB */

__device__ __forceinline__ float sigmoidf_(float x){ return 1.0f/(1.0f+expf(-x)); }
__device__ __forceinline__ short f2bs(float x){
    union { __hip_bfloat16 b; short s; } c; c.b = __float2bfloat16(x); return c.s;
}
__device__ __forceinline__ short8 cvt8(const float* p){
    f32x4 w0 = *(const f32x4*)p;
    f32x4 w1 = *(const f32x4*)(p + 4);
    short8 r;
    r[0]=f2bs(w0[0]); r[1]=f2bs(w0[1]); r[2]=f2bs(w0[2]); r[3]=f2bs(w0[3]);
    r[4]=f2bs(w1[0]); r[5]=f2bs(w1[1]); r[6]=f2bs(w1[2]); r[7]=f2bs(w1[3]);
    return r;
}

// ---------------- K0: concat copies + zero tokd (independent; runs first) ----------------
__global__ void k_prep(const float* pdh, const float* pa, float* out, float* tokd){
    const long n1 = (long)B*T*H/4, n2 = (long)B*T*S/4;
    const long nz = (long)B*EXT/4;
    long i0 = (long)blockIdx.x*256 + threadIdx.x;
    long stride = (long)gridDim.x*256;
    for (long i = i0; i < n1 + n2; i += stride){
        if (i < n1){
            long idx = i*4;
            int b = (int)(idx/(T*H)); int r = (int)(idx%(T*H)); int t = r/H; int k = r%H;
            *(f32x4*)(out + O_DECH + ((long)b*(T+1) + t)*H + k) = *(const f32x4*)(pdh + idx);
        } else {
            long idx = (i - n1)*4;
            int b = (int)(idx/(T*S)); int r = (int)(idx%(T*S)); int t = r/S; int s = r%S;
            *(f32x4*)(out + O_NPA + ((long)b*(T+1) + t)*S + s) = *(const f32x4*)(pa + idx);
        }
    }
    f32x4 z = {0.f,0.f,0.f,0.f};
    for (long i = i0; i < nz; i += stride)
        *(f32x4*)(tokd + i*4) = z;
}

// ---------------- K1: GRU gates via MFMA (emb/lh read inline) ----------------
// grid = G3/16 = 96 blocks, 128 thr. wave0: gi (K=256); wave1: gh (K=512).
__global__ void __launch_bounds__(128) k_gates(const int* tok,
                        const float* emb, const float* lh,
                        const float* Wih, const float* Whh,
                        const float* bih, const float* bhh,
                        float* g, float* Gg){
    int lane = threadIdx.x & 63, wave = threadIdx.x >> 6;
    int row = lane & 15, kg = lane >> 4;
    int j = blockIdx.x*16 + row;
    f32x4 c0={0.f,0.f,0.f,0.f}, c1={0.f,0.f,0.f,0.f};
    f32x4 c2={0.f,0.f,0.f,0.f}, c3={0.f,0.f,0.f,0.f};
    if (wave == 0){
        const float* Wp = Wih + (long)j*E + kg*8;
        const float* a0p = emb + (long)tok[row     ]*E + kg*8;
        const float* a1p = emb + (long)tok[row + 16]*E + kg*8;
        const float* a2p = emb + (long)tok[row + 32]*E + kg*8;
        const float* a3p = emb + (long)tok[row + 48]*E + kg*8;
        #pragma unroll
        for (int ks = 0; ks < 8; ks++){
            short8 bb = cvt8(Wp + ks*32);
            c0 = __builtin_amdgcn_mfma_f32_16x16x32_bf16(cvt8(a0p + ks*32), bb, c0, 0, 0, 0);
            c1 = __builtin_amdgcn_mfma_f32_16x16x32_bf16(cvt8(a1p + ks*32), bb, c1, 0, 0, 0);
            c2 = __builtin_amdgcn_mfma_f32_16x16x32_bf16(cvt8(a2p + ks*32), bb, c2, 0, 0, 0);
            c3 = __builtin_amdgcn_mfma_f32_16x16x32_bf16(cvt8(a3p + ks*32), bb, c3, 0, 0, 0);
        }
        float bi = bih[j];
        #pragma unroll
        for (int r = 0; r < 4; r++){
            int bg = kg*4 + r;
            g[(long)(bg     )*G3 + j] = c0[r] + bi;
            g[(long)(bg + 16)*G3 + j] = c1[r] + bi;
            g[(long)(bg + 32)*G3 + j] = c2[r] + bi;
            g[(long)(bg + 48)*G3 + j] = c3[r] + bi;
        }
    } else {
        const float* Wp = Whh + (long)j*H + kg*8;
        const float* a0p = lh + (long)(row     )*H + kg*8;
        const float* a1p = lh + (long)(row + 16)*H + kg*8;
        const float* a2p = lh + (long)(row + 32)*H + kg*8;
        const float* a3p = lh + (long)(row + 48)*H + kg*8;
        #pragma unroll
        for (int ks = 0; ks < 16; ks++){
            short8 bb = cvt8(Wp + ks*32);
            c0 = __builtin_amdgcn_mfma_f32_16x16x32_bf16(cvt8(a0p + ks*32), bb, c0, 0, 0, 0);
            c1 = __builtin_amdgcn_mfma_f32_16x16x32_bf16(cvt8(a1p + ks*32), bb, c1, 0, 0, 0);
            c2 = __builtin_amdgcn_mfma_f32_16x16x32_bf16(cvt8(a2p + ks*32), bb, c2, 0, 0, 0);
            c3 = __builtin_amdgcn_mfma_f32_16x16x32_bf16(cvt8(a3p + ks*32), bb, c3, 0, 0, 0);
        }
        float bh = bhh[j];
        #pragma unroll
        for (int r = 0; r < 4; r++){
            int bg = kg*4 + r;
            Gg[(long)(bg     )*G3 + j] = c0[r] + bh;
            Gg[(long)(bg + 16)*G3 + j] = c1[r] + bh;
            Gg[(long)(bg + 32)*G3 + j] = c2[r] + bh;
            Gg[(long)(bg + 48)*G3 + j] = c3[r] + bh;
        }
    }
}

// ---------------- K2: GRU combine -> h, hw, hwd ----------------
__global__ void k_gru(const float* g, const float* Gg, const float* lh,
                      const float* wh, const float* wd,
                      float* h, float* hw, float* hwd, float* out){
    int i = blockIdx.x*256 + threadIdx.x;   // B*H
    int b = i >> 9, k = i & 511;
    float ir = g [b*G3 + k], iz = g [b*G3 + H + k], inn = g [b*G3 + 2*H + k];
    float hr = Gg[b*G3 + k], hz = Gg[b*G3 + H + k], hn  = Gg[b*G3 + 2*H + k];
    float r = sigmoidf_(ir + hr), z = sigmoidf_(iz + hz);
    float n = tanhf(inn + r*hn);
    float hp = lh[i];
    float hv = (1.f - z)*n + z*hp;
    h[i] = hv; hw[i] = hv * wh[k]; hwd[i] = hv * wd[k];
    out[O_H + i] = hv;
    out[O_DECH + ((long)b*(T+1) + T)*H + k] = hv;
}

// ---------------- K3: att_dist = h . (w_h * enc) ----------------
__global__ void k_attdist(const float* hw, const float* enc,
                          float* attd, float* out){
    int b = blockIdx.x / (S/4);
    int s = (blockIdx.x % (S/4))*4 + (threadIdx.x >> 6);
    int lane = threadIdx.x & 63;
    const float* ep = enc + ((long)b*S + s)*H + lane*8;
    f32x4 e0 = *(const f32x4*)(ep);
    f32x4 e1 = *(const f32x4*)(ep + 4);
    const float* hwp = hw + b*H + lane*8;
    f32x4 h0 = *(const f32x4*)(hwp);
    f32x4 h1 = *(const f32x4*)(hwp + 4);
    float acc = 0.f;
    #pragma unroll
    for (int m = 0; m < 4; m++) acc += h0[m]*e0[m] + h1[m]*e1[m];
    for (int off = 32; off > 0; off >>= 1) acc += __shfl_xor(acc, off);
    if (lane == 0){
        attd[b*S + s] = acc;
        out[O_NPA + ((long)b*(T+1) + T)*S + s] = acc;
    }
}

// ---------------- K4: small1 = attnorm (blk<64) | decsc (blk>=64) ----------------
__global__ void k_small1(const float* attd, const float* pa,
                         const float* hwd, const float* pdh,
                         float* att, float* sc, float* out){
    __shared__ float tmp[S];
    __shared__ float red[256];
    int tid = threadIdx.x;
    if (blockIdx.x < 64){
        int b = blockIdx.x;
        float part = 0.f;
        for (int s = tid; s < S; s += 256){
            float d = 0.f;
            for (int t = 0; t < T; t++)
                d += expf(pa[((long)b*T + t)*S + s]);
            float e = expf(attd[b*S + s]) / d;
            tmp[s] = e; part += e;
        }
        red[tid] = part; __syncthreads();
        for (int off = 128; off > 0; off >>= 1){
            if (tid < off) red[tid] += red[tid + off];
            __syncthreads();
        }
        float inv = 1.f / red[0];
        for (int s = tid; s < S; s += 256){
            float a = tmp[s] * inv;
            att[b*S + s] = a;
            out[O_ATT + b*S + s] = a;
        }
    } else {
        int b = blockIdx.x - 64;
        int wave = tid >> 6, lane = tid & 63;
        for (int t = wave; t < T; t += 4){
            const float* pp = pdh + ((long)b*T + t)*H + lane*8;
            f32x4 p0 = *(const f32x4*)(pp);
            f32x4 p1 = *(const f32x4*)(pp + 4);
            const float* hp = hwd + b*H + lane*8;
            f32x4 h0 = *(const f32x4*)(hp);
            f32x4 h1 = *(const f32x4*)(hp + 4);
            float acc = 0.f;
            #pragma unroll
            for (int m = 0; m < 4; m++) acc += h0[m]*p0[m] + h1[m]*p1[m];
            for (int off = 32; off > 0; off >>= 1) acc += __shfl_xor(acc, off);
            if (lane == 0) tmp[t] = acc;
        }
        __syncthreads();
        if (wave == 0){
            float xv = (lane < T) ? tmp[lane] : -1e30f;
            float m = xv;
            for (int off = 32; off > 0; off >>= 1) m = fmaxf(m, __shfl_xor(m, off));
            float e = (lane < T) ? expf(xv - m) : 0.f;
            float ssum = e;
            for (int off = 32; off > 0; off >>= 1) ssum += __shfl_xor(ssum, off);
            if (lane < T) sc[b*T + lane] = e / ssum;
        }
    }
}

// ---------------- K5: small2 = encctx(512) | decctx(64) | scatter(50); 512 thr ----------------
__global__ void k_small2(const float* att, const float* enc,
                         const float* sc, const float* pdh,
                         const int* fiv,
                         float* encp, float* dec, float* tokd){
    int blk = blockIdx.x, tid = threadIdx.x;
    if (blk < 512){
        int b = blk >> 3, c = blk & 7;
        float acc = 0.f;
        for (int i = 0; i < S/NCE; i++){
            int s = c*(S/NCE) + i;
            acc += att[b*S + s] * enc[((long)b*S + s)*H + tid];
        }
        encp[(b*NCE + c)*H + tid] = acc;
    } else if (blk < 576){
        int b = blk - 512;
        float acc = 0.f;
        for (int t = 0; t < T; t++)
            acc += sc[b*T + t] * pdh[((long)b*T + t)*H + tid];
        dec[b*H + tid] = acc;
    } else {
        int i = (blk - 576)*512 + tid;   // < B*S = 25600
        int b = i / S;
        atomicAdd(&tokd[(long)b*EXT + fiv[i]], att[i]);
    }
}

// ---------------- K6: projcomb = comb(LDS) + proj GEMM + pgen(et==0) ----------------
__global__ void k_projcomb(const float* h, const float* encp, const float* dec,
                           const float* Woh, const float* boh,
                           const float* Wgen, const float* bgen,
                           short* projbf, float* pg, float* out){
    int blk = blockIdx.x;
    int b = blk >> 4, et = blk & 15;
    int tid = threadIdx.x;
    __shared__ float cl[G3];
    __shared__ float red[256];
    #pragma unroll
    for (int m = 0; m < 2; m++){
        int k = tid + 256*m;
        float v0 = h[b*H + k];
        float v1 = 0.f;
        #pragma unroll
        for (int c = 0; c < NCE; c++) v1 += encp[(b*NCE + c)*H + k];
        float v2 = dec[b*H + k];
        cl[k] = v0; cl[H + k] = v1; cl[2*H + k] = v2;
    }
    __syncthreads();
    int wave = tid >> 6, lane = tid & 63;
    int e0 = et*16 + wave*4;
    const float* w0 = Woh + (long)(e0+0)*G3;
    const float* w1 = Woh + (long)(e0+1)*G3;
    const float* w2 = Woh + (long)(e0+2)*G3;
    const float* w3 = Woh + (long)(e0+3)*G3;
    float a0=0.f, a1=0.f, a2=0.f, a3=0.f;
    #pragma unroll
    for (int m = 0; m < 24; m++){
        int idx = lane + 64*m;
        float c = cl[idx];
        a0 += c * w0[idx]; a1 += c * w1[idx];
        a2 += c * w2[idx]; a3 += c * w3[idx];
    }
    for (int off = 32; off > 0; off >>= 1){
        a0 += __shfl_xor(a0, off); a1 += __shfl_xor(a1, off);
        a2 += __shfl_xor(a2, off); a3 += __shfl_xor(a3, off);
    }
    if (lane == 0){
        projbf[b*E + e0+0] = f2bs(a0 + boh[e0+0]);
        projbf[b*E + e0+1] = f2bs(a1 + boh[e0+1]);
        projbf[b*E + e0+2] = f2bs(a2 + boh[e0+2]);
        projbf[b*E + e0+3] = f2bs(a3 + boh[e0+3]);
    }
    if (et == 0){
        float part = 0.f;
        #pragma unroll
        for (int m = 0; m < 6; m++){
            int j = tid + 256*m;
            part += cl[j] * Wgen[j];
        }
        red[tid] = part; __syncthreads();
        for (int off = 128; off > 0; off >>= 1){
            if (tid < off) red[tid] += red[tid + off];
            __syncthreads();
        }
        if (tid == 0){
            float pv = sigmoidf_(red[0] + bgen[0]);
            pg[b] = pv;
            out[O_PGEN + b] = pv;
        }
    }
}

// ---------------- K7: logits (MFMA; 1 wave = 16 v-rows x ALL 64 batch) ----------------
__global__ void __launch_bounds__(64) k_logits(const short* projbf, const float* Wov,
                         const float* bov, float* out){
    int lane = threadIdx.x;
    int vbase = blockIdx.x * 16;
    int row = lane & 15, kg = lane >> 4;
    f32x4 acc0 = {0.f,0.f,0.f,0.f}, acc1 = {0.f,0.f,0.f,0.f};
    f32x4 acc2 = {0.f,0.f,0.f,0.f}, acc3 = {0.f,0.f,0.f,0.f};
    const float* Bp = Wov + ((long)(vbase + row))*E + kg*8;
    const short* Ap = projbf + row*E + kg*8;
    #pragma unroll
    for (int ks = 0; ks < 8; ks++){
        short8 bb = cvt8(Bp + ks*32);
        short8 a0 = *(const short8*)(Ap + ks*32);
        short8 a1 = *(const short8*)(Ap + 16*E + ks*32);
        short8 a2 = *(const short8*)(Ap + 32*E + ks*32);
        short8 a3 = *(const short8*)(Ap + 48*E + ks*32);
        acc0 = __builtin_amdgcn_mfma_f32_16x16x32_bf16(a0, bb, acc0, 0, 0, 0);
        acc1 = __builtin_amdgcn_mfma_f32_16x16x32_bf16(a1, bb, acc1, 0, 0, 0);
        acc2 = __builtin_amdgcn_mfma_f32_16x16x32_bf16(a2, bb, acc2, 0, 0, 0);
        acc3 = __builtin_amdgcn_mfma_f32_16x16x32_bf16(a3, bb, acc3, 0, 0, 0);
    }
    int v = vbase + row;
    float bv = bov[v];
    #pragma unroll
    for (int r = 0; r < 4; r++){
        int bg = kg*4 + r;
        out[O_PVOCAB + (long)(bg     )*V + v] = acc0[r] + bv;
        out[O_PVOCAB + (long)(bg + 16)*V + v] = acc1[r] + bv;
        out[O_PVOCAB + (long)(bg + 32)*V + v] = acc2[r] + bv;
        out[O_PVOCAB + (long)(bg + 48)*V + v] = acc3[r] + bv;
    }
}

// ---------------- K8: partial exp-sum (no max; logits bounded) ----------------
__global__ void k_smpart(const float* logits, float* psum){
    int b = blockIdx.x / NCH, c = blockIdx.x % NCH;
    const int chunk = (V + NCH - 1)/NCH;
    int start = c*chunk;
    int end = start + chunk; if (end > V) end = V;
    float s = 0.f;
    for (int v = start + threadIdx.x; v < end; v += 256)
        s += expf(logits[(long)b*V + v]);
    __shared__ float ss[256];
    int tid = threadIdx.x;
    ss[tid] = s; __syncthreads();
    for (int off = 128; off > 0; off >>= 1){
        if (tid < off) ss[tid] += ss[tid + off];
        __syncthreads();
    }
    if (tid == 0) psum[blockIdx.x] = ss[0];
}

// ---------------- K9: p_vocab + p_final (sum combine + tokd merge inline) ----------------
__global__ void k_final(const float* psum, const float* pg,
                        const float* tokd, float* out){
    __shared__ float sm[1];
    int b = blockIdx.y;
    if (threadIdx.x < 64){
        int lane = threadIdx.x;
        float s = (lane < NCH) ? psum[b*NCH + lane] : 0.f;
        for (int off = 32; off > 0; off >>= 1) s += __shfl_xor(s, off);
        if (lane == 0) sm[0] = s;
    }
    __syncthreads();
    float inv = 1.f / sm[0];
    int t = blockIdx.x*256 + threadIdx.x;
    if (t >= EXT) return;
    float g = pg[b];
    float td = tokd[(long)b*EXT + t];
    float pf;
    if (t < V){
        long idx = O_PVOCAB + (long)b*V + t;
        float pv = expf(out[idx]) * inv;
        out[idx] = pv;
        pf = pv*g + (1.f - g)*td;
    } else {
        pf = (1.f - g)*td;
    }
    out[O_PFINAL + (long)b*EXT + t] = pf;
}

extern "C" void kernel_launch(void* const* d_in, const int* in_sizes, int n_in,
                              void* d_out, int out_size, void* d_ws, size_t ws_size,
                              hipStream_t stream) {
    const int*   tok  = (const int*)d_in[0];
    const float* pdh  = (const float*)d_in[1];
    const float* lh   = (const float*)d_in[2];
    const float* enc  = (const float*)d_in[3];
    const int*   fiv  = (const int*)d_in[4];
    const float* pa   = (const float*)d_in[5];
    const float* emb  = (const float*)d_in[7];
    const float* Wih  = (const float*)d_in[8];
    const float* Whh  = (const float*)d_in[9];
    const float* bih  = (const float*)d_in[10];
    const float* bhh  = (const float*)d_in[11];
    const float* wh   = (const float*)d_in[12];
    const float* wd   = (const float*)d_in[13];
    const float* Woh  = (const float*)d_in[14];
    const float* boh  = (const float*)d_in[15];
    const float* Wov  = (const float*)d_in[16];
    const float* bov  = (const float*)d_in[17];
    const float* Wgen = (const float*)d_in[18];
    const float* bgen = (const float*)d_in[19];

    float* ws  = (float*)d_ws;
    float* out = (float*)d_out;

    float* g      = ws + OFF_G;
    float* Gg     = ws + OFF_GG;
    float* h      = ws + OFF_H;
    float* hw     = ws + OFF_HW;
    float* hwd    = ws + OFF_HWD;
    float* attd   = ws + OFF_ATTD;
    float* encp   = ws + OFF_ENCP;
    float* dec    = ws + OFF_DEC;
    float* att    = ws + OFF_ATT;
    float* pg     = ws + OFF_PG;
    short* projbf = (short*)(ws + OFF_PROJBF);
    float* psum   = ws + OFF_PSUM;
    float* sc     = ws + OFF_SC;
    float* tokd   = ws + OFF_TOK;

    k_prep    <<<2048, 256, 0, stream>>>(pdh, pa, out, tokd);
    k_gates   <<<G3/16, 128, 0, stream>>>(tok, emb, lh, Wih, Whh, bih, bhh, g, Gg);
    k_gru     <<<(B*H)/256, 256, 0, stream>>>(g, Gg, lh, wh, wd, h, hw, hwd, out);
    k_attdist <<<B*(S/4), 256, 0, stream>>>(hw, enc, attd, out);
    k_small1  <<<128, 256, 0, stream>>>(attd, pa, hwd, pdh, att, sc, out);
    k_small2  <<<626, 512, 0, stream>>>(att, enc, sc, pdh, fiv, encp, dec, tokd);
    k_projcomb<<<B*16, 256, 0, stream>>>(h, encp, dec, Woh, boh, Wgen, bgen,
                                         projbf, pg, out);
    k_logits  <<<V/16, 64, 0, stream>>>(projbf, Wov, bov, out);
    k_smpart  <<<B*NCH, 256, 0, stream>>>(out + O_PVOCAB, psum);
    {
        dim3 grid((EXT + 255)/256, B);
        k_final<<<grid, 256, 0, stream>>>(psum, pg, tokd, out);
    }
}

// Round 10
// 90.513 us; speedup vs baseline: 2.7448x; 1.0951x over previous
//
#include <hip/hip_runtime.h>
#include <hip/hip_bf16.h>

#define B 64
#define T 50
#define S 400
#define H 512
#define E 256
#define V 50000
#define EXT 50250
#define G3 1536
#define NCH 32
#define NCE 8

typedef __attribute__((ext_vector_type(8))) short short8;
typedef __attribute__((ext_vector_type(4))) float f32x4;

// ---- output offsets (f32 elements, return order) ----
#define O_PFINAL 0L
#define O_PGEN   3216000L
#define O_PVOCAB 3216064L
#define O_ATT    6416064L
#define O_DECH   6441664L
#define O_H      8112832L
#define O_NPA    8145600L

// ---- workspace offsets (f32 elements); ws = 256 MB ----
#define OFF_G      0L        /* B*G3 */
#define OFF_GG     98304L    /* B*G3 */
#define OFF_H      196608L   /* B*H  */
#define OFF_HW     229376L   /* B*H  */
#define OFF_HWD    262144L   /* B*H  */
#define OFF_ENCP   294912L   /* B*NCE*H = 262144 */
#define OFF_DEC    557056L   /* B*H  */
#define OFF_E      589824L   /* B*S  */
#define OFF_ESUM   615424L   /* B*NCE */
#define OFF_PG     615936L   /* 64 */
#define OFF_PROJBF 616064L   /* 16384 bf16 = 8192 f32 */
#define OFF_PSUM   624256L   /* B*NCH */
#define OFF_TOK    1048576L  /* B*EXT f32 = 12.9 MB */

__device__ __forceinline__ float sigmoidf_(float x){ return 1.0f/(1.0f+expf(-x)); }
__device__ __forceinline__ short f2bs(float x){
    union { __hip_bfloat16 b; short s; } c; c.b = __float2bfloat16(x); return c.s;
}
__device__ __forceinline__ short8 cvt8(const float* p){
    f32x4 w0 = *(const f32x4*)p;
    f32x4 w1 = *(const f32x4*)(p + 4);
    short8 r;
    r[0]=f2bs(w0[0]); r[1]=f2bs(w0[1]); r[2]=f2bs(w0[2]); r[3]=f2bs(w0[3]);
    r[4]=f2bs(w1[0]); r[5]=f2bs(w1[1]); r[6]=f2bs(w1[2]); r[7]=f2bs(w1[3]);
    return r;
}

// ---------------- K0: concat copies + zero tokd ----------------
__global__ void k_prep(const float* pdh, const float* pa, float* out, float* tokd){
    const long n1 = (long)B*T*H/4, n2 = (long)B*T*S/4;
    const long nz = (long)B*EXT/4;
    long i0 = (long)blockIdx.x*256 + threadIdx.x;
    long stride = (long)gridDim.x*256;
    for (long i = i0; i < n1 + n2; i += stride){
        if (i < n1){
            long idx = i*4;
            int b = (int)(idx/(T*H)); int r = (int)(idx%(T*H)); int t = r/H; int k = r%H;
            *(f32x4*)(out + O_DECH + ((long)b*(T+1) + t)*H + k) = *(const f32x4*)(pdh + idx);
        } else {
            long idx = (i - n1)*4;
            int b = (int)(idx/(T*S)); int r = (int)(idx%(T*S)); int t = r/S; int s = r%S;
            *(f32x4*)(out + O_NPA + ((long)b*(T+1) + t)*S + s) = *(const f32x4*)(pa + idx);
        }
    }
    f32x4 z = {0.f,0.f,0.f,0.f};
    for (long i = i0; i < nz; i += stride)
        *(f32x4*)(tokd + i*4) = z;
}

// ---------------- K1: GRU gates via MFMA ----------------
__global__ void __launch_bounds__(128) k_gates(const int* tok,
                        const float* emb, const float* lh,
                        const float* Wih, const float* Whh,
                        const float* bih, const float* bhh,
                        float* g, float* Gg){
    int lane = threadIdx.x & 63, wave = threadIdx.x >> 6;
    int row = lane & 15, kg = lane >> 4;
    int j = blockIdx.x*16 + row;
    f32x4 c0={0.f,0.f,0.f,0.f}, c1={0.f,0.f,0.f,0.f};
    f32x4 c2={0.f,0.f,0.f,0.f}, c3={0.f,0.f,0.f,0.f};
    if (wave == 0){
        const float* Wp = Wih + (long)j*E + kg*8;
        const float* a0p = emb + (long)tok[row     ]*E + kg*8;
        const float* a1p = emb + (long)tok[row + 16]*E + kg*8;
        const float* a2p = emb + (long)tok[row + 32]*E + kg*8;
        const float* a3p = emb + (long)tok[row + 48]*E + kg*8;
        #pragma unroll
        for (int ks = 0; ks < 8; ks++){
            short8 bb = cvt8(Wp + ks*32);
            c0 = __builtin_amdgcn_mfma_f32_16x16x32_bf16(cvt8(a0p + ks*32), bb, c0, 0, 0, 0);
            c1 = __builtin_amdgcn_mfma_f32_16x16x32_bf16(cvt8(a1p + ks*32), bb, c1, 0, 0, 0);
            c2 = __builtin_amdgcn_mfma_f32_16x16x32_bf16(cvt8(a2p + ks*32), bb, c2, 0, 0, 0);
            c3 = __builtin_amdgcn_mfma_f32_16x16x32_bf16(cvt8(a3p + ks*32), bb, c3, 0, 0, 0);
        }
        float bi = bih[j];
        #pragma unroll
        for (int r = 0; r < 4; r++){
            int bg = kg*4 + r;
            g[(long)(bg     )*G3 + j] = c0[r] + bi;
            g[(long)(bg + 16)*G3 + j] = c1[r] + bi;
            g[(long)(bg + 32)*G3 + j] = c2[r] + bi;
            g[(long)(bg + 48)*G3 + j] = c3[r] + bi;
        }
    } else {
        const float* Wp = Whh + (long)j*H + kg*8;
        const float* a0p = lh + (long)(row     )*H + kg*8;
        const float* a1p = lh + (long)(row + 16)*H + kg*8;
        const float* a2p = lh + (long)(row + 32)*H + kg*8;
        const float* a3p = lh + (long)(row + 48)*H + kg*8;
        #pragma unroll
        for (int ks = 0; ks < 16; ks++){
            short8 bb = cvt8(Wp + ks*32);
            c0 = __builtin_amdgcn_mfma_f32_16x16x32_bf16(cvt8(a0p + ks*32), bb, c0, 0, 0, 0);
            c1 = __builtin_amdgcn_mfma_f32_16x16x32_bf16(cvt8(a1p + ks*32), bb, c1, 0, 0, 0);
            c2 = __builtin_amdgcn_mfma_f32_16x16x32_bf16(cvt8(a2p + ks*32), bb, c2, 0, 0, 0);
            c3 = __builtin_amdgcn_mfma_f32_16x16x32_bf16(cvt8(a3p + ks*32), bb, c3, 0, 0, 0);
        }
        float bh = bhh[j];
        #pragma unroll
        for (int r = 0; r < 4; r++){
            int bg = kg*4 + r;
            Gg[(long)(bg     )*G3 + j] = c0[r] + bh;
            Gg[(long)(bg + 16)*G3 + j] = c1[r] + bh;
            Gg[(long)(bg + 32)*G3 + j] = c2[r] + bh;
            Gg[(long)(bg + 48)*G3 + j] = c3[r] + bh;
        }
    }
}

// ---------------- K2: GRU combine -> h, hw, hwd ----------------
__global__ void k_gru(const float* g, const float* Gg, const float* lh,
                      const float* wh, const float* wd,
                      float* h, float* hw, float* hwd, float* out){
    int i = blockIdx.x*256 + threadIdx.x;   // B*H
    int b = i >> 9, k = i & 511;
    float ir = g [b*G3 + k], iz = g [b*G3 + H + k], inn = g [b*G3 + 2*H + k];
    float hr = Gg[b*G3 + k], hz = Gg[b*G3 + H + k], hn  = Gg[b*G3 + 2*H + k];
    float r = sigmoidf_(ir + hr), z = sigmoidf_(iz + hz);
    float n = tanhf(inn + r*hn);
    float hp = lh[i];
    float hv = (1.f - z)*n + z*hp;
    h[i] = hv; hw[i] = hv * wh[k]; hwd[i] = hv * wd[k];
    out[O_H + i] = hv;
    out[O_DECH + ((long)b*(T+1) + T)*H + k] = hv;
}

// ---------------- K3: fused encoder attention (single enc pass) ----------------
// grid = B*NCE = 512 blocks, 512 thr (8 waves). Wave handles s strided within
// the block's 50-s chunk: attd -> NPA; e=exp(attd)/den -> ws; acc += e*enc.
__global__ void __launch_bounds__(512) k_fused(const float* hw, const float* enc,
                        const float* pa, float* ews, float* esum,
                        float* encp, float* out){
    int blk = blockIdx.x;
    int b = blk >> 3, c = blk & 7;
    int wave = threadIdx.x >> 6, lane = threadIdx.x & 63;
    const float* hwp = hw + b*H + lane*8;
    f32x4 h0 = *(const f32x4*)(hwp);
    f32x4 h1 = *(const f32x4*)(hwp + 4);
    float acc[8] = {0.f,0.f,0.f,0.f,0.f,0.f,0.f,0.f};
    float es = 0.f;
    for (int s0 = wave; s0 < S/NCE; s0 += 8){
        int s = c*(S/NCE) + s0;
        const float* ep = enc + ((long)b*S + s)*H + lane*8;
        f32x4 e0 = *(const f32x4*)(ep);
        f32x4 e1 = *(const f32x4*)(ep + 4);
        float d = 0.f;
        #pragma unroll
        for (int m = 0; m < 4; m++) d += h0[m]*e0[m] + h1[m]*e1[m];
        for (int off = 32; off > 0; off >>= 1) d += __shfl_xor(d, off);
        float pv = (lane < T) ? expf(pa[((long)b*T + lane)*S + s]) : 0.f;
        for (int off = 32; off > 0; off >>= 1) pv += __shfl_xor(pv, off);
        float ee = expf(d) / pv;
        if (lane == 0){
            out[O_NPA + ((long)b*(T+1) + T)*S + s] = d;
            ews[b*S + s] = ee;
        }
        es += ee;
        #pragma unroll
        for (int m = 0; m < 4; m++){ acc[m] += ee*e0[m]; acc[4+m] += ee*e1[m]; }
    }
    __shared__ float lacc[8][H];
    __shared__ float lsum[8];
    #pragma unroll
    for (int m = 0; m < 8; m++) lacc[wave][lane*8 + m] = acc[m];
    if (lane == 0) lsum[wave] = es;
    __syncthreads();
    int tid = threadIdx.x;
    float tt = 0.f;
    #pragma unroll
    for (int w = 0; w < 8; w++) tt += lacc[w][tid];
    encp[((long)b*NCE + c)*H + tid] = tt;
    if (tid == 0){
        float ss = 0.f;
        #pragma unroll
        for (int w = 0; w < 8; w++) ss += lsum[w];
        esum[b*NCE + c] = ss;
    }
}

// ---------------- K4: post1 = dec attention (blk<64) | att+scatter (blk>=64) ----------------
__global__ void __launch_bounds__(512) k_post1(const float* hwd, const float* pdh,
                        const float* ews, const float* esum, const int* fiv,
                        float* dec, float* tokd, float* out){
    int tid = threadIdx.x;
    if (blockIdx.x < 64){
        int b = blockIdx.x;
        __shared__ float sc[T];
        int wave = tid >> 6, lane = tid & 63;
        const float* hp = hwd + b*H + lane*8;
        f32x4 h0 = *(const f32x4*)(hp);
        f32x4 h1 = *(const f32x4*)(hp + 4);
        for (int t = wave; t < T; t += 8){
            const float* pp = pdh + ((long)b*T + t)*H + lane*8;
            f32x4 p0 = *(const f32x4*)(pp);
            f32x4 p1 = *(const f32x4*)(pp + 4);
            float a = 0.f;
            #pragma unroll
            for (int m = 0; m < 4; m++) a += h0[m]*p0[m] + h1[m]*p1[m];
            for (int off = 32; off > 0; off >>= 1) a += __shfl_xor(a, off);
            if (lane == 0) sc[t] = a;
        }
        __syncthreads();
        if (wave == 0){
            float xv = (lane < T) ? sc[lane] : -1e30f;
            float m = xv;
            for (int off = 32; off > 0; off >>= 1) m = fmaxf(m, __shfl_xor(m, off));
            float e = (lane < T) ? expf(xv - m) : 0.f;
            float ssum = e;
            for (int off = 32; off > 0; off >>= 1) ssum += __shfl_xor(ssum, off);
            if (lane < T) sc[lane] = e / ssum;
        }
        __syncthreads();
        float a = 0.f;
        for (int t = 0; t < T; t++)
            a += sc[t] * pdh[((long)b*T + t)*H + tid];
        dec[b*H + tid] = a;
    } else {
        int b = blockIdx.x - 64;
        float inv = 0.f;
        #pragma unroll
        for (int c = 0; c < NCE; c++) inv += esum[b*NCE + c];
        inv = 1.f / inv;
        if (tid < S){
            float a = ews[b*S + tid] * inv;
            out[O_ATT + b*S + tid] = a;
            atomicAdd(&tokd[(long)b*EXT + fiv[b*S + tid]], a);
        }
    }
}

// ---------------- K5: projcomb = comb(LDS, inv-scaled) + proj GEMM + pgen ----------------
__global__ void k_projcomb(const float* h, const float* encp, const float* esum,
                           const float* dec,
                           const float* Woh, const float* boh,
                           const float* Wgen, const float* bgen,
                           short* projbf, float* pg, float* out){
    int blk = blockIdx.x;
    int b = blk >> 4, et = blk & 15;
    int tid = threadIdx.x;
    __shared__ float cl[G3];
    __shared__ float red[256];
    float inv = 0.f;
    #pragma unroll
    for (int c = 0; c < NCE; c++) inv += esum[b*NCE + c];
    inv = 1.f / inv;
    #pragma unroll
    for (int m = 0; m < 2; m++){
        int k = tid + 256*m;
        float v0 = h[b*H + k];
        float v1 = 0.f;
        #pragma unroll
        for (int c = 0; c < NCE; c++) v1 += encp[(b*NCE + c)*H + k];
        float v2 = dec[b*H + k];
        cl[k] = v0; cl[H + k] = v1*inv; cl[2*H + k] = v2;
    }
    __syncthreads();
    int wave = tid >> 6, lane = tid & 63;
    int e0 = et*16 + wave*4;
    const float* w0 = Woh + (long)(e0+0)*G3;
    const float* w1 = Woh + (long)(e0+1)*G3;
    const float* w2 = Woh + (long)(e0+2)*G3;
    const float* w3 = Woh + (long)(e0+3)*G3;
    float a0=0.f, a1=0.f, a2=0.f, a3=0.f;
    #pragma unroll
    for (int m = 0; m < 24; m++){
        int idx = lane + 64*m;
        float c = cl[idx];
        a0 += c * w0[idx]; a1 += c * w1[idx];
        a2 += c * w2[idx]; a3 += c * w3[idx];
    }
    for (int off = 32; off > 0; off >>= 1){
        a0 += __shfl_xor(a0, off); a1 += __shfl_xor(a1, off);
        a2 += __shfl_xor(a2, off); a3 += __shfl_xor(a3, off);
    }
    if (lane == 0){
        projbf[b*E + e0+0] = f2bs(a0 + boh[e0+0]);
        projbf[b*E + e0+1] = f2bs(a1 + boh[e0+1]);
        projbf[b*E + e0+2] = f2bs(a2 + boh[e0+2]);
        projbf[b*E + e0+3] = f2bs(a3 + boh[e0+3]);
    }
    if (et == 0){
        float part = 0.f;
        #pragma unroll
        for (int m = 0; m < 6; m++){
            int j = tid + 256*m;
            part += cl[j] * Wgen[j];
        }
        red[tid] = part; __syncthreads();
        for (int off = 128; off > 0; off >>= 1){
            if (tid < off) red[tid] += red[tid + off];
            __syncthreads();
        }
        if (tid == 0){
            float pv = sigmoidf_(red[0] + bgen[0]);
            pg[b] = pv;
            out[O_PGEN + b] = pv;
        }
    }
}

// ---------------- K6: logits (MFMA; 1 wave = 16 v-rows x ALL 64 batch) ----------------
__global__ void __launch_bounds__(64) k_logits(const short* projbf, const float* Wov,
                         const float* bov, float* out){
    int lane = threadIdx.x;
    int vbase = blockIdx.x * 16;
    int row = lane & 15, kg = lane >> 4;
    f32x4 acc0 = {0.f,0.f,0.f,0.f}, acc1 = {0.f,0.f,0.f,0.f};
    f32x4 acc2 = {0.f,0.f,0.f,0.f}, acc3 = {0.f,0.f,0.f,0.f};
    const float* Bp = Wov + ((long)(vbase + row))*E + kg*8;
    const short* Ap = projbf + row*E + kg*8;
    #pragma unroll
    for (int ks = 0; ks < 8; ks++){
        short8 bb = cvt8(Bp + ks*32);
        short8 a0 = *(const short8*)(Ap + ks*32);
        short8 a1 = *(const short8*)(Ap + 16*E + ks*32);
        short8 a2 = *(const short8*)(Ap + 32*E + ks*32);
        short8 a3 = *(const short8*)(Ap + 48*E + ks*32);
        acc0 = __builtin_amdgcn_mfma_f32_16x16x32_bf16(a0, bb, acc0, 0, 0, 0);
        acc1 = __builtin_amdgcn_mfma_f32_16x16x32_bf16(a1, bb, acc1, 0, 0, 0);
        acc2 = __builtin_amdgcn_mfma_f32_16x16x32_bf16(a2, bb, acc2, 0, 0, 0);
        acc3 = __builtin_amdgcn_mfma_f32_16x16x32_bf16(a3, bb, acc3, 0, 0, 0);
    }
    int v = vbase + row;
    float bv = bov[v];
    #pragma unroll
    for (int r = 0; r < 4; r++){
        int bg = kg*4 + r;
        out[O_PVOCAB + (long)(bg     )*V + v] = acc0[r] + bv;
        out[O_PVOCAB + (long)(bg + 16)*V + v] = acc1[r] + bv;
        out[O_PVOCAB + (long)(bg + 32)*V + v] = acc2[r] + bv;
        out[O_PVOCAB + (long)(bg + 48)*V + v] = acc3[r] + bv;
    }
}

// ---------------- K7: partial exp-sum (logits bounded; no max needed) ----------------
__global__ void k_smpart(const float* logits, float* psum){
    int b = blockIdx.x / NCH, c = blockIdx.x % NCH;
    const int chunk = (V + NCH - 1)/NCH;
    int start = c*chunk;
    int end = start + chunk; if (end > V) end = V;
    float s = 0.f;
    for (int v = start + threadIdx.x; v < end; v += 256)
        s += expf(logits[(long)b*V + v]);
    __shared__ float ss[256];
    int tid = threadIdx.x;
    ss[tid] = s; __syncthreads();
    for (int off = 128; off > 0; off >>= 1){
        if (tid < off) ss[tid] += ss[tid + off];
        __syncthreads();
    }
    if (tid == 0) psum[blockIdx.x] = ss[0];
}

// ---------------- K8: p_vocab + p_final ----------------
__global__ void k_final(const float* psum, const float* pg,
                        const float* tokd, float* out){
    __shared__ float sm[1];
    int b = blockIdx.y;
    if (threadIdx.x < 64){
        int lane = threadIdx.x;
        float s = (lane < NCH) ? psum[b*NCH + lane] : 0.f;
        for (int off = 32; off > 0; off >>= 1) s += __shfl_xor(s, off);
        if (lane == 0) sm[0] = s;
    }
    __syncthreads();
    float inv = 1.f / sm[0];
    int t = blockIdx.x*256 + threadIdx.x;
    if (t >= EXT) return;
    float g = pg[b];
    float td = tokd[(long)b*EXT + t];
    float pf;
    if (t < V){
        long idx = O_PVOCAB + (long)b*V + t;
        float pv = expf(out[idx]) * inv;
        out[idx] = pv;
        pf = pv*g + (1.f - g)*td;
    } else {
        pf = (1.f - g)*td;
    }
    out[O_PFINAL + (long)b*EXT + t] = pf;
}

extern "C" void kernel_launch(void* const* d_in, const int* in_sizes, int n_in,
                              void* d_out, int out_size, void* d_ws, size_t ws_size,
                              hipStream_t stream) {
    const int*   tok  = (const int*)d_in[0];
    const float* pdh  = (const float*)d_in[1];
    const float* lh   = (const float*)d_in[2];
    const float* enc  = (const float*)d_in[3];
    const int*   fiv  = (const int*)d_in[4];
    const float* pa   = (const float*)d_in[5];
    const float* emb  = (const float*)d_in[7];
    const float* Wih  = (const float*)d_in[8];
    const float* Whh  = (const float*)d_in[9];
    const float* bih  = (const float*)d_in[10];
    const float* bhh  = (const float*)d_in[11];
    const float* wh   = (const float*)d_in[12];
    const float* wd   = (const float*)d_in[13];
    const float* Woh  = (const float*)d_in[14];
    const float* boh  = (const float*)d_in[15];
    const float* Wov  = (const float*)d_in[16];
    const float* bov  = (const float*)d_in[17];
    const float* Wgen = (const float*)d_in[18];
    const float* bgen = (const float*)d_in[19];

    float* ws  = (float*)d_ws;
    float* out = (float*)d_out;

    float* g      = ws + OFF_G;
    float* Gg     = ws + OFF_GG;
    float* h      = ws + OFF_H;
    float* hw     = ws + OFF_HW;
    float* hwd    = ws + OFF_HWD;
    float* encp   = ws + OFF_ENCP;
    float* dec    = ws + OFF_DEC;
    float* ews    = ws + OFF_E;
    float* esum   = ws + OFF_ESUM;
    float* pg     = ws + OFF_PG;
    short* projbf = (short*)(ws + OFF_PROJBF);
    float* psum   = ws + OFF_PSUM;
    float* tokd   = ws + OFF_TOK;

    k_prep    <<<2048, 256, 0, stream>>>(pdh, pa, out, tokd);
    k_gates   <<<G3/16, 128, 0, stream>>>(tok, emb, lh, Wih, Whh, bih, bhh, g, Gg);
    k_gru     <<<(B*H)/256, 256, 0, stream>>>(g, Gg, lh, wh, wd, h, hw, hwd, out);
    k_fused   <<<B*NCE, 512, 0, stream>>>(hw, enc, pa, ews, esum, encp, out);
    k_post1   <<<128, 512, 0, stream>>>(hwd, pdh, ews, esum, fiv, dec, tokd, out);
    k_projcomb<<<B*16, 256, 0, stream>>>(h, encp, esum, dec, Woh, boh, Wgen, bgen,
                                         projbf, pg, out);
    k_logits  <<<V/16, 64, 0, stream>>>(projbf, Wov, bov, out);
    k_smpart  <<<B*NCH, 256, 0, stream>>>(out + O_PVOCAB, psum);
    {
        dim3 grid((EXT + 255)/256, B);
        k_final<<<grid, 256, 0, stream>>>(psum, pg, tokd, out);
    }
}